// Round 5
// baseline (1220.662 us; speedup 1.0000x reference)
//
#include <hip/hip_runtime.h>

typedef unsigned short ushort;
typedef unsigned int uint;
typedef __attribute__((ext_vector_type(8))) short short8;
typedef __attribute__((ext_vector_type(4))) float float4v;

#define DEV __device__ __forceinline__

DEV float b2f(ushort u) {
    union { uint i; float f; } v; v.i = ((uint)u) << 16; return v.f;
}
DEV ushort f2b(float f) {
    union { float f; uint i; } v; v.f = f;
    uint x = v.i;
    uint r = x + 0x7fffu + ((x >> 16) & 1u);
    return (ushort)(r >> 16);
}
DEV float leaky(float x, float s) { return x >= 0.f ? x : s * x; }

// ---------------- convert (+local sniff, +zero slice, +flag write) ----------------
struct ConvArgs {
    const void* s[37];
    float* d[37];
    int n[37];
};

__global__ __launch_bounds__(256) void convert_kernel(ConvArgs a, const ushort* __restrict__ x0,
                                                      int* __restrict__ flag) {
    __shared__ int sfp32;
    int tid = threadIdx.x;
    if (tid < 64) {
        int cnt = 0;
        for (int j = 0; j < 8; j++) {
            ushort u = x0[(tid * 8 + j) * 2];
            int e = (u >> 7) & 0xFF;
            if (e >= 100 && e <= 140) cnt++;
        }
#pragma unroll
        for (int m = 1; m < 64; m <<= 1) cnt += __shfl_xor(cnt, m, 64);
        if (tid == 0) sfp32 = (cnt < 256) ? 1 : 0;
    }
    __syncthreads();
    bool fp32 = (sfp32 != 0);
    if (blockIdx.x == 0 && blockIdx.y == 0 && tid == 0) *flag = fp32 ? 1 : 0;

    int ai = blockIdx.y;
    int n = a.n[ai];
    const void* s = a.s[ai];
    float* d = a.d[ai];
    int stride = gridDim.x * blockDim.x;
    if (s == nullptr) {
        for (int i = blockIdx.x * blockDim.x + tid; i < n; i += stride) d[i] = 0.f;
    } else {
        for (int i = blockIdx.x * blockDim.x + tid; i < n; i += stride)
            d[i] = fp32 ? ((const float*)s)[i] : b2f(((const ushort*)s)[i]);
    }
}

// ---------------- CSR build (patch+mesh merged) ----------------
__global__ __launch_bounds__(256) void hist_both(const int* __restrict__ dstP, int* __restrict__ cntP, int EPc,
                                                 const int* __restrict__ dstM, int* __restrict__ cntM, int EMc,
                                                 int PB) {
    bool patch = (int)blockIdx.x < PB;
    const int* dst = patch ? dstP : dstM;
    int* cnt = patch ? cntP : cntM;
    int E = patch ? EPc : EMc;
    int nb = patch ? PB : gridDim.x - PB;
    int b = patch ? blockIdx.x : blockIdx.x - PB;
    int stride = nb * blockDim.x;
    for (int i = b * blockDim.x + threadIdx.x; i < E; i += stride)
        atomicAdd(&cnt[dst[i]], 1);
}

__global__ __launch_bounds__(256) void scan_both(const int* __restrict__ cntP, int* __restrict__ offP,
                                                 int* __restrict__ bsumP, int nP, int SBP,
                                                 const int* __restrict__ cntM, int* __restrict__ offM,
                                                 int* __restrict__ bsumM, int nM) {
    __shared__ int ls[256];
    bool patch = (int)blockIdx.x < SBP;
    const int* cnt = patch ? cntP : cntM;
    int* off = patch ? offP : offM;
    int* bsum = patch ? bsumP : bsumM;
    int n = patch ? nP : nM;
    int b = patch ? blockIdx.x : blockIdx.x - SBP;
    int t = threadIdx.x;
    int base = b * 2048 + t * 8;
    int v[8];
    int s = 0;
#pragma unroll
    for (int i = 0; i < 8; i++) {
        int idx = base + i;
        v[i] = idx < n ? cnt[idx] : 0;
        s += v[i];
    }
    ls[t] = s;
    __syncthreads();
#pragma unroll
    for (int d = 1; d < 256; d <<= 1) {
        int add = (t >= d) ? ls[t - d] : 0;
        __syncthreads();
        ls[t] += add;
        __syncthreads();
    }
    int run = ls[t] - s;
#pragma unroll
    for (int i = 0; i < 8; i++) {
        int idx = base + i;
        if (idx < n) off[idx] = run;
        run += v[i];
    }
    if (t == 255) bsum[b] = ls[255];
}

__global__ __launch_bounds__(256) void fixup_both(const int* __restrict__ bsumP, int* __restrict__ offP,
                                                  int nP, int SBP,
                                                  const int* __restrict__ bsumM, int* __restrict__ offM,
                                                  int nM, int SBM) {
    bool patch = (int)blockIdx.x < SBP;
    const int* bsum = patch ? bsumP : bsumM;
    int* off = patch ? offP : offM;
    int n = patch ? nP : nM;
    int nb = patch ? SBP : SBM;
    int b = patch ? blockIdx.x : blockIdx.x - SBP;
    int t = threadIdx.x;
    int base = 0;
    for (int i = 0; i < b; i++) base += bsum[i];
    int idx0 = b * 2048 + t * 8;
    if (base != 0) {
#pragma unroll
        for (int i = 0; i < 8; i++) {
            int idx = idx0 + i;
            if (idx < n) off[idx] += base;
        }
    }
    if (b == nb - 1 && t == 255) off[n] = base + bsum[b];
}

__global__ __launch_bounds__(256) void scatter_both(const int* __restrict__ srcP, const int* __restrict__ dstP,
                                                    const int* __restrict__ offP, int* __restrict__ curP,
                                                    int* __restrict__ csrP, int EPc,
                                                    const int* __restrict__ srcM, const int* __restrict__ dstM,
                                                    const int* __restrict__ offM, int* __restrict__ curM,
                                                    int* __restrict__ csrM, int EMc, int PB) {
    bool patch = (int)blockIdx.x < PB;
    const int* src = patch ? srcP : srcM;
    const int* dst = patch ? dstP : dstM;
    const int* off = patch ? offP : offM;
    int* cursor = patch ? curP : curM;
    int* csr = patch ? csrP : csrM;
    int E = patch ? EPc : EMc;
    int nb = patch ? PB : gridDim.x - PB;
    int b = patch ? blockIdx.x : blockIdx.x - PB;
    int stride = nb * blockDim.x;
    for (int i = b * blockDim.x + threadIdx.x; i < E; i += stride) {
        int d = dst[i];
        int pos = off[d] + atomicAdd(&cursor[d], 1);
        csr[pos] = src[i];
    }
}

// ---------------- layer-1: el/er only ----------------
__global__ __launch_bounds__(256) void proj1_elr_kernel(const float* __restrict__ x,
                                                        const float* __restrict__ W,
                                                        const float* __restrict__ al,
                                                        const float* __restrict__ ar,
                                                        float* __restrict__ el,
                                                        float* __restrict__ er, int Nn) {
    int t = threadIdx.x;
    int head = t >> 6, lane = t & 63;
    float wv[5];
#pragma unroll
    for (int k = 0; k < 5; k++) wv[k] = W[k * 256 + t];
    float alv = al[t];
    float arv = ar[t];
    int n0 = blockIdx.x * 4;
    int n1 = min(n0 + 4, Nn);
    for (int n = n0; n < n1; n++) {
        float acc = 0.f;
#pragma unroll
        for (int k = 0; k < 5; k++) acc += x[n * 5 + k] * wv[k];
        float pl = acc * alv, pr = acc * arv;
#pragma unroll
        for (int m = 1; m < 64; m <<= 1) {
            pl += __shfl_xor(pl, m, 64);
            pr += __shfl_xor(pr, m, 64);
        }
        if (lane == 0) { el[n * 4 + head] = pl; er[n * 4 + head] = pr; }
    }
}

// ---------------- patch layer-1 aggregation, on-the-fly h (K=5, HD=256, H=4), masked U=4 ----------------
__global__ __launch_bounds__(256) void aggr1_fly_kernel(const float* __restrict__ x,
                                                        const float* __restrict__ W,
                                                        const float* __restrict__ el,
                                                        const float* __restrict__ er,
                                                        const int* __restrict__ off,
                                                        const int* __restrict__ csr,
                                                        float* __restrict__ out, int Nn) {
    int gw = blockIdx.x * 4 + (threadIdx.x >> 6);
    if (gw >= Nn) return;
    int lane = threadIdx.x & 63;
    int c0 = lane * 4;
    int myhead = lane >> 4;
    float w0[5], w1[5], w2[5], w3[5];
#pragma unroll
    for (int k = 0; k < 5; k++) {
        float4 wv = *(const float4*)(W + k * 256 + c0);
        w0[k] = wv.x; w1[k] = wv.y; w2[k] = wv.z; w3[k] = wv.w;
    }
    float erd = er[gw * 4 + myhead];
    float a0 = 0.f, a1 = 0.f, a2 = 0.f, a3 = 0.f, s = 0.f;
    int e0 = off[gw], e1 = off[gw + 1];
    for (int base = e0; base < e1; base += 4) {
        float xv[4][5], w[4];
#pragma unroll
        for (int u = 0; u < 4; u++) {
            int idx = base + u;
            bool ok = idx < e1;
            int src = csr[ok ? idx : base];
#pragma unroll
            for (int k = 0; k < 5; k++) xv[u][k] = x[src * 5 + k];
            float ev = el[src * 4 + myhead] + erd;
            ev = ev >= 0.f ? ev : 0.2f * ev;
            w[u] = ok ? __expf(fminf(ev, 80.f)) : 0.f;
        }
#pragma unroll
        for (int u = 0; u < 4; u++) {
            float h0 = 0.f, h1 = 0.f, h2 = 0.f, h3 = 0.f;
#pragma unroll
            for (int k = 0; k < 5; k++) {
                h0 += xv[u][k] * w0[k]; h1 += xv[u][k] * w1[k];
                h2 += xv[u][k] * w2[k]; h3 += xv[u][k] * w3[k];
            }
            a0 += w[u] * h0; a1 += w[u] * h1; a2 += w[u] * h2; a3 += w[u] * h3;
            s += w[u];
        }
    }
    float inv = 1.f / fmaxf(s, 1e-9f);
    float4 o;
    o.x = leaky(a0 * inv, 0.01f);
    o.y = leaky(a1 * inv, 0.01f);
    o.z = leaky(a2 * inv, 0.01f);
    o.w = leaky(a3 * inv, 0.01f);
    *(float4*)(out + (size_t)gw * 256 + c0) = o;
}

// ---------------- gather aggregation (float4/lane, 1 exp/lane, masked batch) ----------------
template <int H, int LOGD, int HD, int U>
__global__ __launch_bounds__(256) void aggr4_kernel(const float* __restrict__ h,
                                                    const float* __restrict__ el,
                                                    const float* __restrict__ er,
                                                    const int* __restrict__ off,
                                                    const int* __restrict__ csr,
                                                    float* __restrict__ out, int Nn,
                                                    float oslope) {
    int gw = blockIdx.x * 4 + (threadIdx.x >> 6);
    if (gw >= Nn) return;
    int lane = threadIdx.x & 63;
    constexpr int NL = HD / 4;
    bool act = lane < NL;
    int myhead = (lane * 4) >> LOGD;
    float erd = act ? er[gw * H + myhead] : 0.f;
    float a0 = 0.f, a1 = 0.f, a2 = 0.f, a3 = 0.f, s = 0.f;
    int e0 = off[gw], e1 = off[gw + 1];
    for (int base = e0; base < e1; base += U) {
        float w[U];
        float4 hv[U];
#pragma unroll
        for (int u = 0; u < U; u++) {
            int idx = base + u;
            bool ok = idx < e1;
            int src = csr[ok ? idx : base];
            float ev = act ? el[src * H + myhead] + erd : 0.f;
            ev = ev >= 0.f ? ev : 0.2f * ev;
            w[u] = ok ? __expf(fminf(ev, 80.f)) : 0.f;
            hv[u] = act ? *(const float4*)(h + (size_t)src * HD + lane * 4)
                        : make_float4(0.f, 0.f, 0.f, 0.f);
        }
#pragma unroll
        for (int u = 0; u < U; u++) {
            a0 += w[u] * hv[u].x; a1 += w[u] * hv[u].y;
            a2 += w[u] * hv[u].z; a3 += w[u] * hv[u].w;
            s += w[u];
        }
    }
    if (act) {
        float inv = 1.f / fmaxf(s, 1e-9f);
        float4 o;
        o.x = leaky(a0 * inv, oslope);
        o.y = leaky(a1 * inv, oslope);
        o.z = leaky(a2 * inv, oslope);
        o.w = leaky(a3 * inv, oslope);
        *(float4*)(out + (size_t)gw * HD + lane * 4) = o;
    }
}

// final GAT layer: H=2, D=32, HD=64, head-mean + atomic segment-sum, masked U=8
__global__ __launch_bounds__(256) void aggr_mean_kernel(const float* __restrict__ h,
                                                        const float* __restrict__ el,
                                                        const float* __restrict__ er,
                                                        const int* __restrict__ off,
                                                        const int* __restrict__ csr,
                                                        const int* __restrict__ gid,
                                                        float* __restrict__ out_sum,
                                                        float* __restrict__ out_cnt,
                                                        int Nn) {
    int gw = blockIdx.x * 4 + (threadIdx.x >> 6);
    if (gw >= Nn) return;
    int lane = threadIdx.x & 63;
    bool lo32 = lane < 32;
    float erd = lo32 ? er[gw * 2] : er[gw * 2 + 1];
    float acc = 0.f, s = 0.f;
    int e0 = off[gw], e1 = off[gw + 1];
    for (int base = e0; base < e1; base += 8) {
        float w[8], hv[8];
#pragma unroll
        for (int u = 0; u < 8; u++) {
            int idx = base + u;
            bool ok = idx < e1;
            int src = csr[ok ? idx : base];
            float2 e2 = *(const float2*)(el + src * 2);
            float ev = (lo32 ? e2.x : e2.y) + erd;
            ev = ev >= 0.f ? ev : 0.2f * ev;
            w[u] = ok ? __expf(fminf(ev, 80.f)) : 0.f;
            hv[u] = h[(size_t)src * 64 + lane];
        }
#pragma unroll
        for (int u = 0; u < 8; u++) { acc += w[u] * hv[u]; s += w[u]; }
    }
    float y = acc / fmaxf(s, 1e-9f);
    float part = __shfl_xor(y, 32, 64);
    float hm = 0.5f * (y + part);
    if (lo32) {
        int base = gid ? gid[gw] * 32 : 0;
        atomicAdd(&out_sum[base + lane], hm);
    }
    if (lane == 0 && out_cnt) atomicAdd(&out_cnt[gid[gw]], 1.0f);
}

// ---------------- GraphNorm column stats ----------------
__global__ void colstats_kernel(const float* __restrict__ x,
                                float* __restrict__ sum,
                                float* __restrict__ sumsq, int Nn) {
    int C = blockDim.x, c = threadIdx.x;
    float ls = 0.f, lq = 0.f;
    for (int r = blockIdx.x; r < Nn; r += gridDim.x) {
        float v = x[(size_t)r * C + c];
        ls += v; lq += v * v;
    }
    atomicAdd(&sum[c], ls);
    atomicAdd(&sumsq[c], lq);
}

// GraphNorm apply for readout: writes d_out (per flag) + fp32 mesh input
__global__ void gnorm_apply_ro_kernel(const float* __restrict__ x,
                                      const float* __restrict__ sum,
                                      const float* __restrict__ sumsq,
                                      const float* __restrict__ g,
                                      const float* __restrict__ b,
                                      const float* __restrict__ a,
                                      void* __restrict__ doutv,
                                      const int* __restrict__ flag,
                                      float* __restrict__ rof, int Nn) {
    int c = threadIdx.x;  // C = 32
    float invn = 1.f / (float)Nn;
    float mu = sum[c] * invn, ex2 = sumsq[c] * invn;
    float av = a[c];
    float var = ex2 - 2.f * av * mu * mu + av * av * mu * mu;
    float sc = g[c] * rsqrtf(var + 1e-5f);
    float sh = b[c] - sc * av * mu;
    bool fp32 = (*flag != 0);
    for (int r = blockIdx.x; r < Nn; r += gridDim.x) {
        int i = r * 32 + c;
        float v = x[i] * sc + sh;
        rof[i] = v;
        if (fp32) ((float*)doutv)[15 + i] = v;
        else      ((ushort*)doutv)[15 + i] = f2b(v);
    }
}

// ---------------- readout: segment-mean @ pcls + leaky ----------------
__global__ __launch_bounds__(256) void readout_kernel(const float* __restrict__ ro_sum,
                                                      const float* __restrict__ ro_cnt,
                                                      const float* __restrict__ pcls,
                                                      float* __restrict__ ro_lin, int NGc) {
    int idx = blockIdx.x * blockDim.x + threadIdx.x;
    int g = idx >> 5, c = idx & 31;
    if (g >= NGc) return;
    float inv = 1.f / fmaxf(ro_cnt[g], 1.f);
    float acc = 0.f;
#pragma unroll
    for (int k = 0; k < 32; k++) acc += ro_sum[g * 32 + k] * inv * pcls[k * 32 + c];
    ro_lin[g * 32 + c] = leaky(acc, 0.01f);
}

// ---------------- MFMA GEMM: C = gnorm(A) @ B, fused gnfin (prologue) + elr (epilogue) ----------------
template <int K, int N, int H, int LOGD, bool GN>
__global__ __launch_bounds__(256) void gemm_kernel(const float* __restrict__ A,
                                                   const float* __restrict__ B,
                                                   const float* __restrict__ csum,
                                                   const float* __restrict__ g,
                                                   const float* __restrict__ gb,
                                                   const float* __restrict__ ga,
                                                   const float* __restrict__ al,
                                                   const float* __restrict__ ar,
                                                   float* __restrict__ C,
                                                   float* __restrict__ el,
                                                   float* __restrict__ er, int M) {
    constexpr int NT = N / 16;
    constexpr int AROW = 40;
    __shared__ __align__(16) ushort Alds[64 * AROW];
    __shared__ __align__(16) ushort Blds[32 * N];  // swizzled [k/8][n][k%8]
    __shared__ float ScL[256], ShL[256];
    int tid = threadIdx.x;
    int w = tid >> 6, lane = tid & 63, q = lane >> 4, l16 = lane & 15;
    int m0 = blockIdx.x * 64;
    if (GN && tid < K) {
        float invn = 1.f / (float)M;
        float mu = csum[tid] * invn, ex2 = csum[512 + tid] * invn;
        float av = ga[tid];
        float var = ex2 - 2.f * av * mu * mu + av * av * mu * mu;
        float sc = g[tid] * rsqrtf(var + 1e-5f);
        ScL[tid] = sc;
        ShL[tid] = gb[tid] - sc * av * mu;
    }
    float4v acc[NT];
#pragma unroll
    for (int nt = 0; nt < NT; nt++) acc[nt] = (float4v){0.f, 0.f, 0.f, 0.f};

    for (int kc = 0; kc < K; kc += 32) {
        __syncthreads();
        {
#pragma unroll
            for (int it = 0; it < 2; it++) {
                int idx = it * 256 + tid;
                int r = idx >> 3;
                int c4 = (idx & 7) * 4;
                int gr = m0 + r;
                float4 av = {0.f, 0.f, 0.f, 0.f};
                if (gr < M) av = *(const float4*)(A + (size_t)gr * K + kc + c4);
                if (GN) {
                    av.x = av.x * ScL[kc + c4] + ShL[kc + c4];
                    av.y = av.y * ScL[kc + c4 + 1] + ShL[kc + c4 + 1];
                    av.z = av.z * ScL[kc + c4 + 2] + ShL[kc + c4 + 2];
                    av.w = av.w * ScL[kc + c4 + 3] + ShL[kc + c4 + 3];
                }
                uint2 pk;
                pk.x = (uint)f2b(av.x) | ((uint)f2b(av.y) << 16);
                pk.y = (uint)f2b(av.z) | ((uint)f2b(av.w) << 16);
                *(uint2*)(&Alds[r * AROW + c4]) = pk;
            }
        }
        {
            constexpr int PAIRS = 16 * N;
#pragma unroll
            for (int p0 = 0; p0 < PAIRS; p0 += 256) {
                int p = p0 + tid;
                int k_ = p / (N / 2);
                int n0 = (p % (N / 2)) * 2;
                float2 bv = *(const float2*)(B + (size_t)(kc + k_) * N + n0);
                int base = (((k_ >> 3) * N + n0) << 3) + (k_ & 7);
                Blds[base] = f2b(bv.x);
                Blds[base + 8] = f2b(bv.y);
            }
        }
        __syncthreads();
        short8 a = *(const short8*)(&Alds[(w * 16 + l16) * AROW + q * 8]);
#pragma unroll
        for (int nt = 0; nt < NT; nt++) {
            short8 b = *(const short8*)(&Blds[(q * N + nt * 16 + l16) * 8]);
            acc[nt] = __builtin_amdgcn_mfma_f32_16x16x32_bf16(a, b, acc[nt], 0, 0, 0);
        }
    }
    // store C + fused el/er
    float pel[4][H], per[4][H];
#pragma unroll
    for (int i = 0; i < 4; i++)
#pragma unroll
        for (int hh = 0; hh < H; hh++) { pel[i][hh] = 0.f; per[i][hh] = 0.f; }
#pragma unroll
    for (int nt = 0; nt < NT; nt++) {
        int col = nt * 16 + l16;
        float alc = al[col], arc = ar[col];
        constexpr int HSH = LOGD - 4;
        int hh = nt >> HSH;
#pragma unroll
        for (int i = 0; i < 4; i++) {
            int row = m0 + w * 16 + q * 4 + i;
            float v = acc[nt][i];
            if (row < M) C[(size_t)row * N + col] = v;
            pel[i][hh] += v * alc;
            per[i][hh] += v * arc;
        }
    }
#pragma unroll
    for (int i = 0; i < 4; i++) {
#pragma unroll
        for (int hh = 0; hh < H; hh++) {
            float vl = pel[i][hh], vr = per[i][hh];
#pragma unroll
            for (int m = 1; m < 16; m <<= 1) {
                vl += __shfl_xor(vl, m, 64);
                vr += __shfl_xor(vr, m, 64);
            }
            if (l16 == 0) {
                int row = m0 + w * 16 + q * 4 + i;
                if (row < M) { el[row * H + hh] = vl; er[row * H + hh] = vr; }
            }
        }
    }
}

// ---------------- final: node-mean @ mcls ----------------
__global__ __launch_bounds__(64) void final_kernel(const float* __restrict__ msum,
                                                   const float* __restrict__ mcls,
                                                   void* __restrict__ doutv,
                                                   const int* __restrict__ flag, int Nm) {
    int t = threadIdx.x;
    if (t < 15) {
        float inv = 1.f / (float)Nm;
        float acc = 0.f;
#pragma unroll
        for (int c = 0; c < 32; c++) acc += msum[c] * inv * mcls[c * 15 + t];
        if (*flag) ((float*)doutv)[t] = acc;
        else       ((ushort*)doutv)[t] = f2b(acc);
    }
}

extern "C" void kernel_launch(void* const* d_in, const int* in_sizes, int n_in,
                              void* d_out, int out_size, void* d_ws, size_t ws_size,
                              hipStream_t stream) {
    const int NP = 100000, NG = 2000, EP = 800000, NM = 2000, EM = 32000;

    const int* patch_src = (const int*)d_in[1];
    const int* patch_dst = (const int*)d_in[2];
    const int* patch_gid = (const int*)d_in[3];
    const int* mesh_src = (const int*)d_in[4];
    const int* mesh_dst = (const int*)d_in[5];

    char* p = (char*)d_ws;
    auto alloc = [&](size_t bytes) -> char* {
        char* r = p;
        p += (bytes + 255) & ~(size_t)255;
        return r;
    };
    char* zbase = p;
    int* cnt_p = (int*)alloc((size_t)NP * 4);
    int* cursor_p = (int*)alloc((size_t)NP * 4);
    int* cnt_m = (int*)alloc((size_t)NM * 4);
    int* cursor_m = (int*)alloc((size_t)NM * 4);
    float* ro_sum = (float*)alloc((size_t)NG * 32 * 4);
    float* ro_cnt = (float*)alloc((size_t)NG * 4);
    float* msum = (float*)alloc(32 * 4);
    float* colbuf = (float*)alloc(6 * 1024 * 4);
    size_t zbytes = (size_t)(p - zbase);
    int* flag = (int*)alloc(256);
    int* off_p = (int*)alloc((size_t)(NP + 1) * 4);
    int* off_m = (int*)alloc((size_t)(NM + 1) * 4);
    int* bsum_p = (int*)alloc(64 * 4);
    int* bsum_m = (int*)alloc(16 * 4);
    int* csr_p = (int*)alloc((size_t)EP * 4);
    int* csr_m = (int*)alloc((size_t)EM * 4);
    float* el = (float*)alloc((size_t)NP * 4 * 4);
    float* er = (float*)alloc((size_t)NP * 4 * 4);
    float* hbuf = (float*)alloc((size_t)NP * 256 * 4);
    float* gbuf = (float*)alloc((size_t)NP * 256 * 4);
    float* hm = (float*)alloc((size_t)NM * 256 * 4);
    float* gm = (float*)alloc((size_t)NM * 256 * 4);
    float* elm = (float*)alloc((size_t)NM * 4 * 4);
    float* erm = (float*)alloc((size_t)NM * 4 * 4);
    float* ro_lin = (float*)alloc((size_t)NG * 32 * 4);
    float* ro_f = (float*)alloc((size_t)NG * 32 * 4);

    ConvArgs ca;
    float* convp[36];
    int conv_idx[36];
    conv_idx[0] = 0;
    for (int i = 1; i < 36; i++) conv_idx[i] = 5 + i;
    for (int j = 0; j < 36; j++) {
        int ii = conv_idx[j];
        int n = in_sizes[ii];
        float* dd = (float*)alloc((size_t)n * 4);
        ca.s[j] = d_in[ii];
        ca.d[j] = dd;
        ca.n[j] = n;
        convp[j] = dd;
    }
    ca.s[36] = nullptr;
    ca.d[36] = (float*)zbase;
    ca.n[36] = (int)(zbytes / 4);

    const float* xf = convp[0];
    const float *pW1f = convp[1], *pal1f = convp[2], *par1f = convp[3];
    const float *pg1_gf = convp[4], *pg1_bf = convp[5], *pg1_af = convp[6];
    const float *pW2f = convp[7], *pal2f = convp[8], *par2f = convp[9];
    const float *pg2_gf = convp[10], *pg2_bf = convp[11], *pg2_af = convp[12];
    const float *pW3f = convp[13], *pal3f = convp[14], *par3f = convp[15];
    const float* pclsf = convp[16];
    const float *rn_gf = convp[17], *rn_bf2 = convp[18], *rn_af = convp[19];
    const float *mW1f = convp[20], *mal1f = convp[21], *mar1f = convp[22];
    const float *mg1_gf = convp[23], *mg1_bf = convp[24], *mg1_af = convp[25];
    const float *mW2f = convp[26], *mal2f = convp[27], *mar2f = convp[28];
    const float *mg2_gf = convp[29], *mg2_bf = convp[30], *mg2_af = convp[31];
    const float *mW3f = convp[32], *mal3f = convp[33], *mar3f = convp[34];
    const float* mclsf = convp[35];

    convert_kernel<<<dim3(16, 37), 256, 0, stream>>>(ca, (const ushort*)d_in[0], flag);

    const int SBP = (NP + 2047) / 2048, SBM = (NM + 2047) / 2048;
    hist_both<<<512 + 64, 256, 0, stream>>>(patch_dst, cnt_p, EP, mesh_dst, cnt_m, EM, 512);
    scan_both<<<SBP + SBM, 256, 0, stream>>>(cnt_p, off_p, bsum_p, NP, SBP, cnt_m, off_m, bsum_m, NM);
    fixup_both<<<SBP + SBM, 256, 0, stream>>>(bsum_p, off_p, NP, SBP, bsum_m, off_m, NM, SBM);
    scatter_both<<<512 + 64, 256, 0, stream>>>(patch_src, patch_dst, off_p, cursor_p, csr_p, EP,
                                               mesh_src, mesh_dst, off_m, cursor_m, csr_m, EM, 512);

    int gP = (NP + 3) / 4, gM = (NM + 3) / 4;
    int gT = (NP + 63) / 64, gTm = (NM + 63) / 64;
    float* cb0 = colbuf + 0 * 1024;
    float* cb1 = colbuf + 1 * 1024;
    float* cb2 = colbuf + 2 * 1024;
    float* cb3 = colbuf + 3 * 1024;
    float* cb4 = colbuf + 4 * 1024;

    // ---- patch GAT layer 1 ----
    proj1_elr_kernel<<<gP, 256, 0, stream>>>(xf, pW1f, pal1f, par1f, el, er, NP);
    aggr1_fly_kernel<<<gP, 256, 0, stream>>>(xf, pW1f, el, er, off_p, csr_p, gbuf, NP);
    colstats_kernel<<<256, 256, 0, stream>>>(gbuf, cb0, cb0 + 512, NP);

    // ---- patch GAT layer 2 ----
    gemm_kernel<256, 192, 3, 6, true><<<gT, 256, 0, stream>>>(
        gbuf, pW2f, cb0, pg1_gf, pg1_bf, pg1_af, pal2f, par2f, hbuf, el, er, NP);
    aggr4_kernel<3, 6, 192, 8><<<gP, 256, 0, stream>>>(hbuf, el, er, off_p, csr_p, gbuf, NP, 0.01f);
    colstats_kernel<<<256, 192, 0, stream>>>(gbuf, cb1, cb1 + 512, NP);

    // ---- patch GAT layer 3 + readout ----
    gemm_kernel<192, 64, 2, 5, true><<<gT, 256, 0, stream>>>(
        gbuf, pW3f, cb1, pg2_gf, pg2_bf, pg2_af, pal3f, par3f, hbuf, el, er, NP);
    aggr_mean_kernel<<<gP, 256, 0, stream>>>(hbuf, el, er, off_p, csr_p, patch_gid,
                                             ro_sum, ro_cnt, NP);

    readout_kernel<<<(NG * 32 + 255) / 256, 256, 0, stream>>>(ro_sum, ro_cnt, pclsf, ro_lin, NG);
    colstats_kernel<<<64, 32, 0, stream>>>(ro_lin, cb2, cb2 + 512, NG);
    gnorm_apply_ro_kernel<<<64, 32, 0, stream>>>(ro_lin, cb2, cb2 + 512, rn_gf, rn_bf2, rn_af,
                                                 d_out, flag, ro_f, NG);

    // ---- mesh GAT layer 1 ----
    gemm_kernel<32, 256, 4, 6, false><<<gTm, 256, 0, stream>>>(
        ro_f, mW1f, nullptr, nullptr, nullptr, nullptr, mal1f, mar1f, hm, elm, erm, NM);
    aggr4_kernel<4, 6, 256, 4><<<gM, 256, 0, stream>>>(hm, elm, erm, off_m, csr_m, gm, NM, 0.01f);
    colstats_kernel<<<64, 256, 0, stream>>>(gm, cb3, cb3 + 512, NM);

    // ---- mesh GAT layer 2 ----
    gemm_kernel<256, 96, 3, 5, true><<<gTm, 256, 0, stream>>>(
        gm, mW2f, cb3, mg1_gf, mg1_bf, mg1_af, mal2f, mar2f, hm, elm, erm, NM);
    aggr4_kernel<3, 5, 96, 8><<<gM, 256, 0, stream>>>(hm, elm, erm, off_m, csr_m, gm, NM, 0.01f);
    colstats_kernel<<<64, 96, 0, stream>>>(gm, cb4, cb4 + 512, NM);

    // ---- mesh GAT layer 3 ----
    gemm_kernel<96, 64, 2, 5, true><<<gTm, 256, 0, stream>>>(
        gm, mW3f, cb4, mg2_gf, mg2_bf, mg2_af, mal3f, mar3f, hm, elm, erm, NM);
    aggr_mean_kernel<<<gM, 256, 0, stream>>>(hm, elm, erm, off_m, csr_m, nullptr,
                                             msum, nullptr, NM);
    final_kernel<<<1, 64, 0, stream>>>(msum, mclsf, d_out, flag, NM);

    (void)n_in; (void)out_size; (void)ws_size;
}

// Round 6
// 1126.816 us; speedup vs baseline: 1.0833x; 1.0833x over previous
//
#include <hip/hip_runtime.h>

typedef unsigned short ushort;
typedef unsigned int uint;
typedef __attribute__((ext_vector_type(8))) short short8;
typedef __attribute__((ext_vector_type(4))) float float4v;

#define DEV __device__ __forceinline__

DEV float b2f(ushort u) {
    union { uint i; float f; } v; v.i = ((uint)u) << 16; return v.f;
}
DEV ushort f2b(float f) {
    union { float f; uint i; } v; v.f = f;
    uint x = v.i;
    uint r = x + 0x7fffu + ((x >> 16) & 1u);
    return (ushort)(r >> 16);
}
DEV float leaky(float x, float s) { return x >= 0.f ? x : s * x; }

// ---------------- convert (+local sniff, +zero slice, +flag write) ----------------
struct ConvArgs {
    const void* s[37];
    float* d[37];
    int n[37];
};

__global__ __launch_bounds__(256) void convert_kernel(ConvArgs a, const ushort* __restrict__ x0,
                                                      int* __restrict__ flag) {
    __shared__ int sfp32;
    int tid = threadIdx.x;
    if (tid < 64) {
        int cnt = 0;
        for (int j = 0; j < 8; j++) {
            ushort u = x0[(tid * 8 + j) * 2];
            int e = (u >> 7) & 0xFF;
            if (e >= 100 && e <= 140) cnt++;
        }
#pragma unroll
        for (int m = 1; m < 64; m <<= 1) cnt += __shfl_xor(cnt, m, 64);
        if (tid == 0) sfp32 = (cnt < 256) ? 1 : 0;
    }
    __syncthreads();
    bool fp32 = (sfp32 != 0);
    if (blockIdx.x == 0 && blockIdx.y == 0 && tid == 0) *flag = fp32 ? 1 : 0;

    int ai = blockIdx.y;
    int n = a.n[ai];
    const void* s = a.s[ai];
    float* d = a.d[ai];
    int stride = gridDim.x * blockDim.x;
    if (s == nullptr) {
        for (int i = blockIdx.x * blockDim.x + tid; i < n; i += stride) d[i] = 0.f;
    } else {
        for (int i = blockIdx.x * blockDim.x + tid; i < n; i += stride)
            d[i] = fp32 ? ((const float*)s)[i] : b2f(((const ushort*)s)[i]);
    }
}

// ---------------- CSR build (patch+mesh merged) ----------------
__global__ __launch_bounds__(256) void hist_both(const int* __restrict__ dstP, int* __restrict__ cntP, int EPc,
                                                 const int* __restrict__ dstM, int* __restrict__ cntM, int EMc,
                                                 int PB) {
    bool patch = (int)blockIdx.x < PB;
    const int* dst = patch ? dstP : dstM;
    int* cnt = patch ? cntP : cntM;
    int E = patch ? EPc : EMc;
    int nb = patch ? PB : gridDim.x - PB;
    int b = patch ? blockIdx.x : blockIdx.x - PB;
    int stride = nb * blockDim.x;
    for (int i = b * blockDim.x + threadIdx.x; i < E; i += stride)
        atomicAdd(&cnt[dst[i]], 1);
}

__global__ __launch_bounds__(256) void scan_both(const int* __restrict__ cntP, int* __restrict__ offP,
                                                 int* __restrict__ bsumP, int nP, int SBP,
                                                 const int* __restrict__ cntM, int* __restrict__ offM,
                                                 int* __restrict__ bsumM, int nM) {
    __shared__ int ls[256];
    bool patch = (int)blockIdx.x < SBP;
    const int* cnt = patch ? cntP : cntM;
    int* off = patch ? offP : offM;
    int* bsum = patch ? bsumP : bsumM;
    int n = patch ? nP : nM;
    int b = patch ? blockIdx.x : blockIdx.x - SBP;
    int t = threadIdx.x;
    int base = b * 2048 + t * 8;
    int v[8];
    int s = 0;
#pragma unroll
    for (int i = 0; i < 8; i++) {
        int idx = base + i;
        v[i] = idx < n ? cnt[idx] : 0;
        s += v[i];
    }
    ls[t] = s;
    __syncthreads();
#pragma unroll
    for (int d = 1; d < 256; d <<= 1) {
        int add = (t >= d) ? ls[t - d] : 0;
        __syncthreads();
        ls[t] += add;
        __syncthreads();
    }
    int run = ls[t] - s;
#pragma unroll
    for (int i = 0; i < 8; i++) {
        int idx = base + i;
        if (idx < n) off[idx] = run;
        run += v[i];
    }
    if (t == 255) bsum[b] = ls[255];
}

__global__ __launch_bounds__(256) void fixup_both(const int* __restrict__ bsumP, int* __restrict__ offP,
                                                  int nP, int SBP,
                                                  const int* __restrict__ bsumM, int* __restrict__ offM,
                                                  int nM, int SBM) {
    bool patch = (int)blockIdx.x < SBP;
    const int* bsum = patch ? bsumP : bsumM;
    int* off = patch ? offP : offM;
    int n = patch ? nP : nM;
    int nb = patch ? SBP : SBM;
    int b = patch ? blockIdx.x : blockIdx.x - SBP;
    int t = threadIdx.x;
    int base = 0;
    for (int i = 0; i < b; i++) base += bsum[i];
    int idx0 = b * 2048 + t * 8;
    if (base != 0) {
#pragma unroll
        for (int i = 0; i < 8; i++) {
            int idx = idx0 + i;
            if (idx < n) off[idx] += base;
        }
    }
    if (b == nb - 1 && t == 255) off[n] = base + bsum[b];
}

__global__ __launch_bounds__(256) void scatter_both(const int* __restrict__ srcP, const int* __restrict__ dstP,
                                                    const int* __restrict__ offP, int* __restrict__ curP,
                                                    int* __restrict__ csrP, int EPc,
                                                    const int* __restrict__ srcM, const int* __restrict__ dstM,
                                                    const int* __restrict__ offM, int* __restrict__ curM,
                                                    int* __restrict__ csrM, int EMc, int PB) {
    bool patch = (int)blockIdx.x < PB;
    const int* src = patch ? srcP : srcM;
    const int* dst = patch ? dstP : dstM;
    const int* off = patch ? offP : offM;
    int* cursor = patch ? curP : curM;
    int* csr = patch ? csrP : csrM;
    int E = patch ? EPc : EMc;
    int nb = patch ? PB : gridDim.x - PB;
    int b = patch ? blockIdx.x : blockIdx.x - PB;
    int stride = nb * blockDim.x;
    for (int i = b * blockDim.x + threadIdx.x; i < E; i += stride) {
        int d = dst[i];
        int pos = off[d] + atomicAdd(&cursor[d], 1);
        csr[pos] = src[i];
    }
}

// ---------------- layer-1: el/er only ----------------
__global__ __launch_bounds__(256) void proj1_elr_kernel(const float* __restrict__ x,
                                                        const float* __restrict__ W,
                                                        const float* __restrict__ al,
                                                        const float* __restrict__ ar,
                                                        float* __restrict__ el,
                                                        float* __restrict__ er, int Nn) {
    int t = threadIdx.x;
    int head = t >> 6, lane = t & 63;
    float wv[5];
#pragma unroll
    for (int k = 0; k < 5; k++) wv[k] = W[k * 256 + t];
    float alv = al[t];
    float arv = ar[t];
    int n0 = blockIdx.x * 4;
    int n1 = min(n0 + 4, Nn);
    for (int n = n0; n < n1; n++) {
        float acc = 0.f;
#pragma unroll
        for (int k = 0; k < 5; k++) acc += x[n * 5 + k] * wv[k];
        float pl = acc * alv, pr = acc * arv;
#pragma unroll
        for (int m = 1; m < 64; m <<= 1) {
            pl += __shfl_xor(pl, m, 64);
            pr += __shfl_xor(pr, m, 64);
        }
        if (lane == 0) { el[n * 4 + head] = pl; er[n * 4 + head] = pr; }
    }
}

// ---------------- patch layer-1 aggregation, on-the-fly h (K=5, HD=256, H=4) ----------------
__global__ __launch_bounds__(256) void aggr1_fly_kernel(const float* __restrict__ x,
                                                        const float* __restrict__ W,
                                                        const float* __restrict__ el,
                                                        const float* __restrict__ er,
                                                        const int* __restrict__ off,
                                                        const int* __restrict__ csr,
                                                        float* __restrict__ out, int Nn) {
    int gw = blockIdx.x * 4 + (threadIdx.x >> 6);
    if (gw >= Nn) return;
    int lane = threadIdx.x & 63;
    int c0 = lane * 4;
    int myhead = lane >> 4;
    float w0[5], w1[5], w2[5], w3[5];
#pragma unroll
    for (int k = 0; k < 5; k++) {
        float4 wv = *(const float4*)(W + k * 256 + c0);
        w0[k] = wv.x; w1[k] = wv.y; w2[k] = wv.z; w3[k] = wv.w;
    }
    float erd = er[gw * 4 + myhead];
    float a0 = 0.f, a1 = 0.f, a2 = 0.f, a3 = 0.f, s = 0.f;
    int e = off[gw], e1 = off[gw + 1];
    for (; e + 2 <= e1; e += 2) {
        int sA = csr[e], sB = csr[e + 1];
        float xA[5], xB[5];
#pragma unroll
        for (int k = 0; k < 5; k++) { xA[k] = x[sA * 5 + k]; xB[k] = x[sB * 5 + k]; }
        float evA = el[sA * 4 + myhead] + erd;
        float evB = el[sB * 4 + myhead] + erd;
        evA = evA >= 0.f ? evA : 0.2f * evA;
        evB = evB >= 0.f ? evB : 0.2f * evB;
        float wA = __expf(fminf(evA, 80.f));
        float wB = __expf(fminf(evB, 80.f));
        float hA0 = 0.f, hA1 = 0.f, hA2 = 0.f, hA3 = 0.f;
        float hB0 = 0.f, hB1 = 0.f, hB2 = 0.f, hB3 = 0.f;
#pragma unroll
        for (int k = 0; k < 5; k++) {
            hA0 += xA[k] * w0[k]; hA1 += xA[k] * w1[k];
            hA2 += xA[k] * w2[k]; hA3 += xA[k] * w3[k];
            hB0 += xB[k] * w0[k]; hB1 += xB[k] * w1[k];
            hB2 += xB[k] * w2[k]; hB3 += xB[k] * w3[k];
        }
        a0 += wA * hA0 + wB * hB0;
        a1 += wA * hA1 + wB * hB1;
        a2 += wA * hA2 + wB * hB2;
        a3 += wA * hA3 + wB * hB3;
        s += wA + wB;
    }
    for (; e < e1; e++) {
        int sA = csr[e];
        float xA[5];
#pragma unroll
        for (int k = 0; k < 5; k++) xA[k] = x[sA * 5 + k];
        float evA = el[sA * 4 + myhead] + erd;
        evA = evA >= 0.f ? evA : 0.2f * evA;
        float wA = __expf(fminf(evA, 80.f));
        float hA0 = 0.f, hA1 = 0.f, hA2 = 0.f, hA3 = 0.f;
#pragma unroll
        for (int k = 0; k < 5; k++) {
            hA0 += xA[k] * w0[k]; hA1 += xA[k] * w1[k];
            hA2 += xA[k] * w2[k]; hA3 += xA[k] * w3[k];
        }
        a0 += wA * hA0; a1 += wA * hA1; a2 += wA * hA2; a3 += wA * hA3;
        s += wA;
    }
    float inv = 1.f / fmaxf(s, 1e-9f);
    float4 o;
    o.x = leaky(a0 * inv, 0.01f);
    o.y = leaky(a1 * inv, 0.01f);
    o.z = leaky(a2 * inv, 0.01f);
    o.w = leaky(a3 * inv, 0.01f);
    *(float4*)(out + (size_t)gw * 256 + c0) = o;
}

// ---------------- gather aggregation: full batches (no masks) + ONE masked tail ----------------
template <int H, int LOGD, int HD, int U>
__global__ __launch_bounds__(256) void aggr4_kernel(const float* __restrict__ h,
                                                    const float* __restrict__ el,
                                                    const float* __restrict__ er,
                                                    const int* __restrict__ off,
                                                    const int* __restrict__ csr,
                                                    float* __restrict__ out, int Nn,
                                                    float oslope) {
    int gw = blockIdx.x * 4 + (threadIdx.x >> 6);
    if (gw >= Nn) return;
    int lane = threadIdx.x & 63;
    constexpr int NL = HD / 4;
    bool act = lane < NL;
    int myhead = (lane * 4) >> LOGD;
    float erd = act ? er[gw * H + myhead] : 0.f;
    float a0 = 0.f, a1 = 0.f, a2 = 0.f, a3 = 0.f, s = 0.f;
    int e = off[gw], e1 = off[gw + 1];
    // full batches — clean address path, max MLP
    for (; e + U <= e1; e += U) {
        int srcs[U];
#pragma unroll
        for (int u = 0; u < U; u++) srcs[u] = csr[e + u];
        float w[U];
        float4 hv[U];
#pragma unroll
        for (int u = 0; u < U; u++) {
            float ev = act ? el[srcs[u] * H + myhead] + erd : 0.f;
            ev = ev >= 0.f ? ev : 0.2f * ev;
            w[u] = __expf(fminf(ev, 80.f));
            hv[u] = act ? *(const float4*)(h + (size_t)srcs[u] * HD + lane * 4)
                        : make_float4(0.f, 0.f, 0.f, 0.f);
        }
#pragma unroll
        for (int u = 0; u < U; u++) {
            a0 += w[u] * hv[u].x; a1 += w[u] * hv[u].y;
            a2 += w[u] * hv[u].z; a3 += w[u] * hv[u].w;
            s += w[u];
        }
    }
    // single masked tail batch (≤ U-1 real edges)
    if (e < e1) {
        float w[U];
        float4 hv[U];
#pragma unroll
        for (int u = 0; u < U; u++) {
            int idx = e + u;
            bool ok = idx < e1;
            int src = csr[ok ? idx : e];
            float ev = act ? el[src * H + myhead] + erd : 0.f;
            ev = ev >= 0.f ? ev : 0.2f * ev;
            w[u] = ok ? __expf(fminf(ev, 80.f)) : 0.f;
            hv[u] = act ? *(const float4*)(h + (size_t)src * HD + lane * 4)
                        : make_float4(0.f, 0.f, 0.f, 0.f);
        }
#pragma unroll
        for (int u = 0; u < U; u++) {
            a0 += w[u] * hv[u].x; a1 += w[u] * hv[u].y;
            a2 += w[u] * hv[u].z; a3 += w[u] * hv[u].w;
            s += w[u];
        }
    }
    if (act) {
        float inv = 1.f / fmaxf(s, 1e-9f);
        float4 o;
        o.x = leaky(a0 * inv, oslope);
        o.y = leaky(a1 * inv, oslope);
        o.z = leaky(a2 * inv, oslope);
        o.w = leaky(a3 * inv, oslope);
        *(float4*)(out + (size_t)gw * HD + lane * 4) = o;
    }
}

// final GAT layer: H=2, D=32, HD=64 — full U=8 batches + one masked tail
__global__ __launch_bounds__(256) void aggr_mean_kernel(const float* __restrict__ h,
                                                        const float* __restrict__ el,
                                                        const float* __restrict__ er,
                                                        const int* __restrict__ off,
                                                        const int* __restrict__ csr,
                                                        const int* __restrict__ gid,
                                                        float* __restrict__ out_sum,
                                                        float* __restrict__ out_cnt,
                                                        int Nn) {
    int gw = blockIdx.x * 4 + (threadIdx.x >> 6);
    if (gw >= Nn) return;
    int lane = threadIdx.x & 63;
    bool lo32 = lane < 32;
    float erd = lo32 ? er[gw * 2] : er[gw * 2 + 1];
    float acc = 0.f, s = 0.f;
    int e = off[gw], e1 = off[gw + 1];
    for (; e + 8 <= e1; e += 8) {
        int srcs[8];
#pragma unroll
        for (int u = 0; u < 8; u++) srcs[u] = csr[e + u];
        float w[8], hv[8];
#pragma unroll
        for (int u = 0; u < 8; u++) {
            float2 e2 = *(const float2*)(el + srcs[u] * 2);
            float ev = (lo32 ? e2.x : e2.y) + erd;
            ev = ev >= 0.f ? ev : 0.2f * ev;
            w[u] = __expf(fminf(ev, 80.f));
            hv[u] = h[(size_t)srcs[u] * 64 + lane];
        }
#pragma unroll
        for (int u = 0; u < 8; u++) { acc += w[u] * hv[u]; s += w[u]; }
    }
    if (e < e1) {
        float w[8], hv[8];
#pragma unroll
        for (int u = 0; u < 8; u++) {
            int idx = e + u;
            bool ok = idx < e1;
            int src = csr[ok ? idx : e];
            float2 e2 = *(const float2*)(el + src * 2);
            float ev = (lo32 ? e2.x : e2.y) + erd;
            ev = ev >= 0.f ? ev : 0.2f * ev;
            w[u] = ok ? __expf(fminf(ev, 80.f)) : 0.f;
            hv[u] = h[(size_t)src * 64 + lane];
        }
#pragma unroll
        for (int u = 0; u < 8; u++) { acc += w[u] * hv[u]; s += w[u]; }
    }
    float y = acc / fmaxf(s, 1e-9f);
    float part = __shfl_xor(y, 32, 64);
    float hm = 0.5f * (y + part);
    if (lo32) {
        int base = gid ? gid[gw] * 32 : 0;
        atomicAdd(&out_sum[base + lane], hm);
    }
    if (lane == 0 && out_cnt) atomicAdd(&out_cnt[gid[gw]], 1.0f);
}

// ---------------- GraphNorm column stats ----------------
__global__ void colstats_kernel(const float* __restrict__ x,
                                float* __restrict__ sum,
                                float* __restrict__ sumsq, int Nn) {
    int C = blockDim.x, c = threadIdx.x;
    float ls = 0.f, lq = 0.f;
    for (int r = blockIdx.x; r < Nn; r += gridDim.x) {
        float v = x[(size_t)r * C + c];
        ls += v; lq += v * v;
    }
    atomicAdd(&sum[c], ls);
    atomicAdd(&sumsq[c], lq);
}

// GraphNorm apply for readout: writes d_out (per flag) + fp32 mesh input
__global__ void gnorm_apply_ro_kernel(const float* __restrict__ x,
                                      const float* __restrict__ sum,
                                      const float* __restrict__ sumsq,
                                      const float* __restrict__ g,
                                      const float* __restrict__ b,
                                      const float* __restrict__ a,
                                      void* __restrict__ doutv,
                                      const int* __restrict__ flag,
                                      float* __restrict__ rof, int Nn) {
    int c = threadIdx.x;  // C = 32
    float invn = 1.f / (float)Nn;
    float mu = sum[c] * invn, ex2 = sumsq[c] * invn;
    float av = a[c];
    float var = ex2 - 2.f * av * mu * mu + av * av * mu * mu;
    float sc = g[c] * rsqrtf(var + 1e-5f);
    float sh = b[c] - sc * av * mu;
    bool fp32 = (*flag != 0);
    for (int r = blockIdx.x; r < Nn; r += gridDim.x) {
        int i = r * 32 + c;
        float v = x[i] * sc + sh;
        rof[i] = v;
        if (fp32) ((float*)doutv)[15 + i] = v;
        else      ((ushort*)doutv)[15 + i] = f2b(v);
    }
}

// ---------------- readout: segment-mean @ pcls + leaky ----------------
__global__ __launch_bounds__(256) void readout_kernel(const float* __restrict__ ro_sum,
                                                      const float* __restrict__ ro_cnt,
                                                      const float* __restrict__ pcls,
                                                      float* __restrict__ ro_lin, int NGc) {
    int idx = blockIdx.x * blockDim.x + threadIdx.x;
    int g = idx >> 5, c = idx & 31;
    if (g >= NGc) return;
    float inv = 1.f / fmaxf(ro_cnt[g], 1.f);
    float acc = 0.f;
#pragma unroll
    for (int k = 0; k < 32; k++) acc += ro_sum[g * 32 + k] * inv * pcls[k * 32 + c];
    ro_lin[g * 32 + c] = leaky(acc, 0.01f);
}

// ---------------- MFMA GEMM: C = gnorm(A) @ B, fused gnfin (prologue) + elr (epilogue) ----------------
template <int K, int N, int H, int LOGD, bool GN>
__global__ __launch_bounds__(256) void gemm_kernel(const float* __restrict__ A,
                                                   const float* __restrict__ B,
                                                   const float* __restrict__ csum,
                                                   const float* __restrict__ g,
                                                   const float* __restrict__ gb,
                                                   const float* __restrict__ ga,
                                                   const float* __restrict__ al,
                                                   const float* __restrict__ ar,
                                                   float* __restrict__ C,
                                                   float* __restrict__ el,
                                                   float* __restrict__ er, int M) {
    constexpr int NT = N / 16;
    constexpr int AROW = 40;
    __shared__ __align__(16) ushort Alds[64 * AROW];
    __shared__ __align__(16) ushort Blds[32 * N];  // swizzled [k/8][n][k%8]
    __shared__ float ScL[256], ShL[256];
    int tid = threadIdx.x;
    int w = tid >> 6, lane = tid & 63, q = lane >> 4, l16 = lane & 15;
    int m0 = blockIdx.x * 64;
    if (GN && tid < K) {
        float invn = 1.f / (float)M;
        float mu = csum[tid] * invn, ex2 = csum[512 + tid] * invn;
        float av = ga[tid];
        float var = ex2 - 2.f * av * mu * mu + av * av * mu * mu;
        float sc = g[tid] * rsqrtf(var + 1e-5f);
        ScL[tid] = sc;
        ShL[tid] = gb[tid] - sc * av * mu;
    }
    float4v acc[NT];
#pragma unroll
    for (int nt = 0; nt < NT; nt++) acc[nt] = (float4v){0.f, 0.f, 0.f, 0.f};

    for (int kc = 0; kc < K; kc += 32) {
        __syncthreads();
        {
#pragma unroll
            for (int it = 0; it < 2; it++) {
                int idx = it * 256 + tid;
                int r = idx >> 3;
                int c4 = (idx & 7) * 4;
                int gr = m0 + r;
                float4 av = {0.f, 0.f, 0.f, 0.f};
                if (gr < M) av = *(const float4*)(A + (size_t)gr * K + kc + c4);
                if (GN) {
                    av.x = av.x * ScL[kc + c4] + ShL[kc + c4];
                    av.y = av.y * ScL[kc + c4 + 1] + ShL[kc + c4 + 1];
                    av.z = av.z * ScL[kc + c4 + 2] + ShL[kc + c4 + 2];
                    av.w = av.w * ScL[kc + c4 + 3] + ShL[kc + c4 + 3];
                }
                uint2 pk;
                pk.x = (uint)f2b(av.x) | ((uint)f2b(av.y) << 16);
                pk.y = (uint)f2b(av.z) | ((uint)f2b(av.w) << 16);
                *(uint2*)(&Alds[r * AROW + c4]) = pk;
            }
        }
        {
            constexpr int PAIRS = 16 * N;
#pragma unroll
            for (int p0 = 0; p0 < PAIRS; p0 += 256) {
                int p = p0 + tid;
                int k_ = p / (N / 2);
                int n0 = (p % (N / 2)) * 2;
                float2 bv = *(const float2*)(B + (size_t)(kc + k_) * N + n0);
                int base = (((k_ >> 3) * N + n0) << 3) + (k_ & 7);
                Blds[base] = f2b(bv.x);
                Blds[base + 8] = f2b(bv.y);
            }
        }
        __syncthreads();
        short8 a = *(const short8*)(&Alds[(w * 16 + l16) * AROW + q * 8]);
#pragma unroll
        for (int nt = 0; nt < NT; nt++) {
            short8 b = *(const short8*)(&Blds[(q * N + nt * 16 + l16) * 8]);
            acc[nt] = __builtin_amdgcn_mfma_f32_16x16x32_bf16(a, b, acc[nt], 0, 0, 0);
        }
    }
    // store C + fused el/er
    float pel[4][H], per[4][H];
#pragma unroll
    for (int i = 0; i < 4; i++)
#pragma unroll
        for (int hh = 0; hh < H; hh++) { pel[i][hh] = 0.f; per[i][hh] = 0.f; }
#pragma unroll
    for (int nt = 0; nt < NT; nt++) {
        int col = nt * 16 + l16;
        float alc = al[col], arc = ar[col];
        constexpr int HSH = LOGD - 4;
        int hh = nt >> HSH;
#pragma unroll
        for (int i = 0; i < 4; i++) {
            int row = m0 + w * 16 + q * 4 + i;
            float v = acc[nt][i];
            if (row < M) C[(size_t)row * N + col] = v;
            pel[i][hh] += v * alc;
            per[i][hh] += v * arc;
        }
    }
#pragma unroll
    for (int i = 0; i < 4; i++) {
#pragma unroll
        for (int hh = 0; hh < H; hh++) {
            float vl = pel[i][hh], vr = per[i][hh];
#pragma unroll
            for (int m = 1; m < 16; m <<= 1) {
                vl += __shfl_xor(vl, m, 64);
                vr += __shfl_xor(vr, m, 64);
            }
            if (l16 == 0) {
                int row = m0 + w * 16 + q * 4 + i;
                if (row < M) { el[row * H + hh] = vl; er[row * H + hh] = vr; }
            }
        }
    }
}

// ---------------- final: node-mean @ mcls ----------------
__global__ __launch_bounds__(64) void final_kernel(const float* __restrict__ msum,
                                                   const float* __restrict__ mcls,
                                                   void* __restrict__ doutv,
                                                   const int* __restrict__ flag, int Nm) {
    int t = threadIdx.x;
    if (t < 15) {
        float inv = 1.f / (float)Nm;
        float acc = 0.f;
#pragma unroll
        for (int c = 0; c < 32; c++) acc += msum[c] * inv * mcls[c * 15 + t];
        if (*flag) ((float*)doutv)[t] = acc;
        else       ((ushort*)doutv)[t] = f2b(acc);
    }
}

extern "C" void kernel_launch(void* const* d_in, const int* in_sizes, int n_in,
                              void* d_out, int out_size, void* d_ws, size_t ws_size,
                              hipStream_t stream) {
    const int NP = 100000, NG = 2000, EP = 800000, NM = 2000, EM = 32000;

    const int* patch_src = (const int*)d_in[1];
    const int* patch_dst = (const int*)d_in[2];
    const int* patch_gid = (const int*)d_in[3];
    const int* mesh_src = (const int*)d_in[4];
    const int* mesh_dst = (const int*)d_in[5];

    char* p = (char*)d_ws;
    auto alloc = [&](size_t bytes) -> char* {
        char* r = p;
        p += (bytes + 255) & ~(size_t)255;
        return r;
    };
    char* zbase = p;
    int* cnt_p = (int*)alloc((size_t)NP * 4);
    int* cursor_p = (int*)alloc((size_t)NP * 4);
    int* cnt_m = (int*)alloc((size_t)NM * 4);
    int* cursor_m = (int*)alloc((size_t)NM * 4);
    float* ro_sum = (float*)alloc((size_t)NG * 32 * 4);
    float* ro_cnt = (float*)alloc((size_t)NG * 4);
    float* msum = (float*)alloc(32 * 4);
    float* colbuf = (float*)alloc(6 * 1024 * 4);
    size_t zbytes = (size_t)(p - zbase);
    int* flag = (int*)alloc(256);
    int* off_p = (int*)alloc((size_t)(NP + 1) * 4);
    int* off_m = (int*)alloc((size_t)(NM + 1) * 4);
    int* bsum_p = (int*)alloc(64 * 4);
    int* bsum_m = (int*)alloc(16 * 4);
    int* csr_p = (int*)alloc((size_t)EP * 4);
    int* csr_m = (int*)alloc((size_t)EM * 4);
    float* el = (float*)alloc((size_t)NP * 4 * 4);
    float* er = (float*)alloc((size_t)NP * 4 * 4);
    float* hbuf = (float*)alloc((size_t)NP * 256 * 4);
    float* gbuf = (float*)alloc((size_t)NP * 256 * 4);
    float* hm = (float*)alloc((size_t)NM * 256 * 4);
    float* gm = (float*)alloc((size_t)NM * 256 * 4);
    float* elm = (float*)alloc((size_t)NM * 4 * 4);
    float* erm = (float*)alloc((size_t)NM * 4 * 4);
    float* ro_lin = (float*)alloc((size_t)NG * 32 * 4);
    float* ro_f = (float*)alloc((size_t)NG * 32 * 4);

    ConvArgs ca;
    float* convp[36];
    int conv_idx[36];
    conv_idx[0] = 0;
    for (int i = 1; i < 36; i++) conv_idx[i] = 5 + i;
    for (int j = 0; j < 36; j++) {
        int ii = conv_idx[j];
        int n = in_sizes[ii];
        float* dd = (float*)alloc((size_t)n * 4);
        ca.s[j] = d_in[ii];
        ca.d[j] = dd;
        ca.n[j] = n;
        convp[j] = dd;
    }
    ca.s[36] = nullptr;
    ca.d[36] = (float*)zbase;
    ca.n[36] = (int)(zbytes / 4);

    const float* xf = convp[0];
    const float *pW1f = convp[1], *pal1f = convp[2], *par1f = convp[3];
    const float *pg1_gf = convp[4], *pg1_bf = convp[5], *pg1_af = convp[6];
    const float *pW2f = convp[7], *pal2f = convp[8], *par2f = convp[9];
    const float *pg2_gf = convp[10], *pg2_bf = convp[11], *pg2_af = convp[12];
    const float *pW3f = convp[13], *pal3f = convp[14], *par3f = convp[15];
    const float* pclsf = convp[16];
    const float *rn_gf = convp[17], *rn_bf2 = convp[18], *rn_af = convp[19];
    const float *mW1f = convp[20], *mal1f = convp[21], *mar1f = convp[22];
    const float *mg1_gf = convp[23], *mg1_bf = convp[24], *mg1_af = convp[25];
    const float *mW2f = convp[26], *mal2f = convp[27], *mar2f = convp[28];
    const float *mg2_gf = convp[29], *mg2_bf = convp[30], *mg2_af = convp[31];
    const float *mW3f = convp[32], *mal3f = convp[33], *mar3f = convp[34];
    const float* mclsf = convp[35];

    convert_kernel<<<dim3(16, 37), 256, 0, stream>>>(ca, (const ushort*)d_in[0], flag);

    const int SBP = (NP + 2047) / 2048, SBM = (NM + 2047) / 2048;
    hist_both<<<512 + 64, 256, 0, stream>>>(patch_dst, cnt_p, EP, mesh_dst, cnt_m, EM, 512);
    scan_both<<<SBP + SBM, 256, 0, stream>>>(cnt_p, off_p, bsum_p, NP, SBP, cnt_m, off_m, bsum_m, NM);
    fixup_both<<<SBP + SBM, 256, 0, stream>>>(bsum_p, off_p, NP, SBP, bsum_m, off_m, NM, SBM);
    scatter_both<<<512 + 64, 256, 0, stream>>>(patch_src, patch_dst, off_p, cursor_p, csr_p, EP,
                                               mesh_src, mesh_dst, off_m, cursor_m, csr_m, EM, 512);

    int gP = (NP + 3) / 4, gM = (NM + 3) / 4;
    int gT = (NP + 63) / 64, gTm = (NM + 63) / 64;
    float* cb0 = colbuf + 0 * 1024;
    float* cb1 = colbuf + 1 * 1024;
    float* cb2 = colbuf + 2 * 1024;
    float* cb3 = colbuf + 3 * 1024;
    float* cb4 = colbuf + 4 * 1024;

    // ---- patch GAT layer 1 ----
    proj1_elr_kernel<<<gP, 256, 0, stream>>>(xf, pW1f, pal1f, par1f, el, er, NP);
    aggr1_fly_kernel<<<gP, 256, 0, stream>>>(xf, pW1f, el, er, off_p, csr_p, gbuf, NP);
    colstats_kernel<<<256, 256, 0, stream>>>(gbuf, cb0, cb0 + 512, NP);

    // ---- patch GAT layer 2 ----
    gemm_kernel<256, 192, 3, 6, true><<<gT, 256, 0, stream>>>(
        gbuf, pW2f, cb0, pg1_gf, pg1_bf, pg1_af, pal2f, par2f, hbuf, el, er, NP);
    aggr4_kernel<3, 6, 192, 4><<<gP, 256, 0, stream>>>(hbuf, el, er, off_p, csr_p, gbuf, NP, 0.01f);
    colstats_kernel<<<256, 192, 0, stream>>>(gbuf, cb1, cb1 + 512, NP);

    // ---- patch GAT layer 3 + readout ----
    gemm_kernel<192, 64, 2, 5, true><<<gT, 256, 0, stream>>>(
        gbuf, pW3f, cb1, pg2_gf, pg2_bf, pg2_af, pal3f, par3f, hbuf, el, er, NP);
    aggr_mean_kernel<<<gP, 256, 0, stream>>>(hbuf, el, er, off_p, csr_p, patch_gid,
                                             ro_sum, ro_cnt, NP);

    readout_kernel<<<(NG * 32 + 255) / 256, 256, 0, stream>>>(ro_sum, ro_cnt, pclsf, ro_lin, NG);
    colstats_kernel<<<64, 32, 0, stream>>>(ro_lin, cb2, cb2 + 512, NG);
    gnorm_apply_ro_kernel<<<64, 32, 0, stream>>>(ro_lin, cb2, cb2 + 512, rn_gf, rn_bf2, rn_af,
                                                 d_out, flag, ro_f, NG);

    // ---- mesh GAT layer 1 ----
    gemm_kernel<32, 256, 4, 6, false><<<gTm, 256, 0, stream>>>(
        ro_f, mW1f, nullptr, nullptr, nullptr, nullptr, mal1f, mar1f, hm, elm, erm, NM);
    aggr4_kernel<4, 6, 256, 4><<<gM, 256, 0, stream>>>(hm, elm, erm, off_m, csr_m, gm, NM, 0.01f);
    colstats_kernel<<<64, 256, 0, stream>>>(gm, cb3, cb3 + 512, NM);

    // ---- mesh GAT layer 2 ----
    gemm_kernel<256, 96, 3, 5, true><<<gTm, 256, 0, stream>>>(
        gm, mW2f, cb3, mg1_gf, mg1_bf, mg1_af, mal2f, mar2f, hm, elm, erm, NM);
    aggr4_kernel<3, 5, 96, 4><<<gM, 256, 0, stream>>>(hm, elm, erm, off_m, csr_m, gm, NM, 0.01f);
    colstats_kernel<<<64, 96, 0, stream>>>(gm, cb4, cb4 + 512, NM);

    // ---- mesh GAT layer 3 ----
    gemm_kernel<96, 64, 2, 5, true><<<gTm, 256, 0, stream>>>(
        gm, mW3f, cb4, mg2_gf, mg2_bf, mg2_af, mal3f, mar3f, hm, elm, erm, NM);
    aggr_mean_kernel<<<gM, 256, 0, stream>>>(hm, elm, erm, off_m, csr_m, nullptr,
                                             msum, nullptr, NM);
    final_kernel<<<1, 64, 0, stream>>>(msum, mclsf, d_out, flag, NM);

    (void)n_in; (void)out_size; (void)ws_size;
}

// Round 7
// 1070.563 us; speedup vs baseline: 1.1402x; 1.0525x over previous
//
#include <hip/hip_runtime.h>

typedef unsigned short ushort;
typedef unsigned int uint;
typedef __attribute__((ext_vector_type(8))) short short8;
typedef __attribute__((ext_vector_type(4))) float float4v;

#define DEV __device__ __forceinline__

DEV float b2f(ushort u) {
    union { uint i; float f; } v; v.i = ((uint)u) << 16; return v.f;
}
DEV ushort f2b(float f) {
    union { float f; uint i; } v; v.f = f;
    uint x = v.i;
    uint r = x + 0x7fffu + ((x >> 16) & 1u);
    return (ushort)(r >> 16);
}
DEV float leaky(float x, float s) { return x >= 0.f ? x : s * x; }

// ---------------- convert (+local sniff, +zero slice, +flag write) ----------------
struct ConvArgs {
    const void* s[37];
    float* d[37];
    int n[37];
};

__global__ __launch_bounds__(256) void convert_kernel(ConvArgs a, const ushort* __restrict__ x0,
                                                      int* __restrict__ flag) {
    __shared__ int sfp32;
    int tid = threadIdx.x;
    if (tid < 64) {
        int cnt = 0;
        for (int j = 0; j < 8; j++) {
            ushort u = x0[(tid * 8 + j) * 2];
            int e = (u >> 7) & 0xFF;
            if (e >= 100 && e <= 140) cnt++;
        }
#pragma unroll
        for (int m = 1; m < 64; m <<= 1) cnt += __shfl_xor(cnt, m, 64);
        if (tid == 0) sfp32 = (cnt < 256) ? 1 : 0;
    }
    __syncthreads();
    bool fp32 = (sfp32 != 0);
    if (blockIdx.x == 0 && blockIdx.y == 0 && tid == 0) *flag = fp32 ? 1 : 0;

    int ai = blockIdx.y;
    int n = a.n[ai];
    const void* s = a.s[ai];
    float* d = a.d[ai];
    int stride = gridDim.x * blockDim.x;
    if (s == nullptr) {
        for (int i = blockIdx.x * blockDim.x + tid; i < n; i += stride) d[i] = 0.f;
    } else {
        for (int i = blockIdx.x * blockDim.x + tid; i < n; i += stride)
            d[i] = fp32 ? ((const float*)s)[i] : b2f(((const ushort*)s)[i]);
    }
}

// ---------------- CSR build (patch+mesh merged) ----------------
__global__ __launch_bounds__(256) void hist_both(const int* __restrict__ dstP, int* __restrict__ cntP, int EPc,
                                                 const int* __restrict__ dstM, int* __restrict__ cntM, int EMc,
                                                 int PB) {
    bool patch = (int)blockIdx.x < PB;
    const int* dst = patch ? dstP : dstM;
    int* cnt = patch ? cntP : cntM;
    int E = patch ? EPc : EMc;
    int nb = patch ? PB : gridDim.x - PB;
    int b = patch ? blockIdx.x : blockIdx.x - PB;
    int stride = nb * blockDim.x;
    for (int i = b * blockDim.x + threadIdx.x; i < E; i += stride)
        atomicAdd(&cnt[dst[i]], 1);
}

__global__ __launch_bounds__(256) void scan_both(const int* __restrict__ cntP, int* __restrict__ offP,
                                                 int* __restrict__ bsumP, int nP, int SBP,
                                                 const int* __restrict__ cntM, int* __restrict__ offM,
                                                 int* __restrict__ bsumM, int nM) {
    __shared__ int ls[256];
    bool patch = (int)blockIdx.x < SBP;
    const int* cnt = patch ? cntP : cntM;
    int* off = patch ? offP : offM;
    int* bsum = patch ? bsumP : bsumM;
    int n = patch ? nP : nM;
    int b = patch ? blockIdx.x : blockIdx.x - SBP;
    int t = threadIdx.x;
    int base = b * 2048 + t * 8;
    int v[8];
    int s = 0;
#pragma unroll
    for (int i = 0; i < 8; i++) {
        int idx = base + i;
        v[i] = idx < n ? cnt[idx] : 0;
        s += v[i];
    }
    ls[t] = s;
    __syncthreads();
#pragma unroll
    for (int d = 1; d < 256; d <<= 1) {
        int add = (t >= d) ? ls[t - d] : 0;
        __syncthreads();
        ls[t] += add;
        __syncthreads();
    }
    int run = ls[t] - s;
#pragma unroll
    for (int i = 0; i < 8; i++) {
        int idx = base + i;
        if (idx < n) off[idx] = run;
        run += v[i];
    }
    if (t == 255) bsum[b] = ls[255];
}

__global__ __launch_bounds__(256) void fixup_both(const int* __restrict__ bsumP, int* __restrict__ offP,
                                                  int nP, int SBP,
                                                  const int* __restrict__ bsumM, int* __restrict__ offM,
                                                  int nM, int SBM) {
    bool patch = (int)blockIdx.x < SBP;
    const int* bsum = patch ? bsumP : bsumM;
    int* off = patch ? offP : offM;
    int n = patch ? nP : nM;
    int nb = patch ? SBP : SBM;
    int b = patch ? blockIdx.x : blockIdx.x - SBP;
    int t = threadIdx.x;
    int base = 0;
    for (int i = 0; i < b; i++) base += bsum[i];
    int idx0 = b * 2048 + t * 8;
    if (base != 0) {
#pragma unroll
        for (int i = 0; i < 8; i++) {
            int idx = idx0 + i;
            if (idx < n) off[idx] += base;
        }
    }
    if (b == nb - 1 && t == 255) off[n] = base + bsum[b];
}

__global__ __launch_bounds__(256) void scatter_both(const int* __restrict__ srcP, const int* __restrict__ dstP,
                                                    const int* __restrict__ offP, int* __restrict__ curP,
                                                    int* __restrict__ csrP, int EPc,
                                                    const int* __restrict__ srcM, const int* __restrict__ dstM,
                                                    const int* __restrict__ offM, int* __restrict__ curM,
                                                    int* __restrict__ csrM, int EMc, int PB) {
    bool patch = (int)blockIdx.x < PB;
    const int* src = patch ? srcP : srcM;
    const int* dst = patch ? dstP : dstM;
    const int* off = patch ? offP : offM;
    int* cursor = patch ? curP : curM;
    int* csr = patch ? csrP : csrM;
    int E = patch ? EPc : EMc;
    int nb = patch ? PB : gridDim.x - PB;
    int b = patch ? blockIdx.x : blockIdx.x - PB;
    int stride = nb * blockDim.x;
    for (int i = b * blockDim.x + threadIdx.x; i < E; i += stride) {
        int d = dst[i];
        int pos = off[d] + atomicAdd(&cursor[d], 1);
        csr[pos] = src[i];
    }
}

// ---------------- layer-1: el/er only ----------------
__global__ __launch_bounds__(256) void proj1_elr_kernel(const float* __restrict__ x,
                                                        const float* __restrict__ W,
                                                        const float* __restrict__ al,
                                                        const float* __restrict__ ar,
                                                        float* __restrict__ el,
                                                        float* __restrict__ er, int Nn) {
    int t = threadIdx.x;
    int head = t >> 6, lane = t & 63;
    float wv[5];
#pragma unroll
    for (int k = 0; k < 5; k++) wv[k] = W[k * 256 + t];
    float alv = al[t];
    float arv = ar[t];
    int n0 = blockIdx.x * 4;
    int n1 = min(n0 + 4, Nn);
    for (int n = n0; n < n1; n++) {
        float acc = 0.f;
#pragma unroll
        for (int k = 0; k < 5; k++) acc += x[n * 5 + k] * wv[k];
        float pl = acc * alv, pr = acc * arv;
#pragma unroll
        for (int m = 1; m < 64; m <<= 1) {
            pl += __shfl_xor(pl, m, 64);
            pr += __shfl_xor(pr, m, 64);
        }
        if (lane == 0) { el[n * 4 + head] = pl; er[n * 4 + head] = pr; }
    }
}

// ---------------- patch layer-1 aggregation, on-the-fly h (K=5, HD=256, H=4) ----------------
__global__ __launch_bounds__(256) void aggr1_fly_kernel(const float* __restrict__ x,
                                                        const float* __restrict__ W,
                                                        const float* __restrict__ el,
                                                        const float* __restrict__ er,
                                                        const int* __restrict__ off,
                                                        const int* __restrict__ csr,
                                                        float* __restrict__ out, int Nn) {
    int gw = blockIdx.x * 4 + (threadIdx.x >> 6);
    if (gw >= Nn) return;
    int lane = threadIdx.x & 63;
    int c0 = lane * 4;
    int myhead = lane >> 4;
    float w0[5], w1[5], w2[5], w3[5];
#pragma unroll
    for (int k = 0; k < 5; k++) {
        float4 wv = *(const float4*)(W + k * 256 + c0);
        w0[k] = wv.x; w1[k] = wv.y; w2[k] = wv.z; w3[k] = wv.w;
    }
    float erd = er[gw * 4 + myhead];
    float a0 = 0.f, a1 = 0.f, a2 = 0.f, a3 = 0.f, s = 0.f;
    int e = off[gw], e1 = off[gw + 1];
    for (; e + 2 <= e1; e += 2) {
        int sA = csr[e], sB = csr[e + 1];
        // load phase
        float xA[5], xB[5];
        float eA = el[sA * 4 + myhead], eB = el[sB * 4 + myhead];
#pragma unroll
        for (int k = 0; k < 5; k++) { xA[k] = x[sA * 5 + k]; xB[k] = x[sB * 5 + k]; }
        // compute phase
        float evA = eA + erd, evB = eB + erd;
        evA = evA >= 0.f ? evA : 0.2f * evA;
        evB = evB >= 0.f ? evB : 0.2f * evB;
        float wA = __expf(fminf(evA, 80.f));
        float wB = __expf(fminf(evB, 80.f));
        float hA0 = 0.f, hA1 = 0.f, hA2 = 0.f, hA3 = 0.f;
        float hB0 = 0.f, hB1 = 0.f, hB2 = 0.f, hB3 = 0.f;
#pragma unroll
        for (int k = 0; k < 5; k++) {
            hA0 += xA[k] * w0[k]; hA1 += xA[k] * w1[k];
            hA2 += xA[k] * w2[k]; hA3 += xA[k] * w3[k];
            hB0 += xB[k] * w0[k]; hB1 += xB[k] * w1[k];
            hB2 += xB[k] * w2[k]; hB3 += xB[k] * w3[k];
        }
        a0 += wA * hA0 + wB * hB0;
        a1 += wA * hA1 + wB * hB1;
        a2 += wA * hA2 + wB * hB2;
        a3 += wA * hA3 + wB * hB3;
        s += wA + wB;
    }
    for (; e < e1; e++) {
        int sA = csr[e];
        float xA[5];
#pragma unroll
        for (int k = 0; k < 5; k++) xA[k] = x[sA * 5 + k];
        float evA = el[sA * 4 + myhead] + erd;
        evA = evA >= 0.f ? evA : 0.2f * evA;
        float wA = __expf(fminf(evA, 80.f));
        float hA0 = 0.f, hA1 = 0.f, hA2 = 0.f, hA3 = 0.f;
#pragma unroll
        for (int k = 0; k < 5; k++) {
            hA0 += xA[k] * w0[k]; hA1 += xA[k] * w1[k];
            hA2 += xA[k] * w2[k]; hA3 += xA[k] * w3[k];
        }
        a0 += wA * hA0; a1 += wA * hA1; a2 += wA * hA2; a3 += wA * hA3;
        s += wA;
    }
    float inv = 1.f / fmaxf(s, 1e-9f);
    float4 o;
    o.x = leaky(a0 * inv, 0.01f);
    o.y = leaky(a1 * inv, 0.01f);
    o.z = leaky(a2 * inv, 0.01f);
    o.w = leaky(a3 * inv, 0.01f);
    *(float4*)(out + (size_t)gw * 256 + c0) = o;
}

// ---------------- gather aggregation (bf16 h, load/compute split, masked tail) ----------------
template <int H, int LOGD, int HD, int U>
__global__ __launch_bounds__(256) void aggr4_kernel(const ushort* __restrict__ h,
                                                    const float* __restrict__ el,
                                                    const float* __restrict__ er,
                                                    const int* __restrict__ off,
                                                    const int* __restrict__ csr,
                                                    float* __restrict__ out, int Nn,
                                                    float oslope) {
    int gw = blockIdx.x * 4 + (threadIdx.x >> 6);
    if (gw >= Nn) return;
    int lane = threadIdx.x & 63;
    constexpr int NL = HD / 4;
    bool act = lane < NL;
    int myhead = (lane * 4) >> LOGD;
    float erd = act ? er[gw * H + myhead] : 0.f;
    float a0 = 0.f, a1 = 0.f, a2 = 0.f, a3 = 0.f, s = 0.f;
    int e = off[gw], e1 = off[gw + 1];
    for (; e + U <= e1; e += U) {
        int srcs[U];
#pragma unroll
        for (int u = 0; u < U; u++) srcs[u] = csr[e + u];
        // load phase: all el + h loads, no compute
        float elv[U];
        uint2 hr[U];
#pragma unroll
        for (int u = 0; u < U; u++) {
            elv[u] = act ? el[srcs[u] * H + myhead] : 0.f;
            hr[u] = act ? *(const uint2*)(h + (size_t)srcs[u] * HD + lane * 4)
                        : make_uint2(0, 0);
        }
        // compute phase
#pragma unroll
        for (int u = 0; u < U; u++) {
            float ev = elv[u] + erd;
            ev = ev >= 0.f ? ev : 0.2f * ev;
            float w = __expf(fminf(ev, 80.f));
            a0 += w * b2f((ushort)hr[u].x);
            a1 += w * b2f((ushort)(hr[u].x >> 16));
            a2 += w * b2f((ushort)hr[u].y);
            a3 += w * b2f((ushort)(hr[u].y >> 16));
            s += w;
        }
    }
    if (e < e1) {
        float elv[U];
        uint2 hr[U];
        bool okk[U];
#pragma unroll
        for (int u = 0; u < U; u++) {
            int idx = e + u;
            okk[u] = idx < e1;
            int src = csr[okk[u] ? idx : e];
            elv[u] = act ? el[src * H + myhead] : 0.f;
            hr[u] = act ? *(const uint2*)(h + (size_t)src * HD + lane * 4)
                        : make_uint2(0, 0);
        }
#pragma unroll
        for (int u = 0; u < U; u++) {
            float ev = elv[u] + erd;
            ev = ev >= 0.f ? ev : 0.2f * ev;
            float w = okk[u] ? __expf(fminf(ev, 80.f)) : 0.f;
            a0 += w * b2f((ushort)hr[u].x);
            a1 += w * b2f((ushort)(hr[u].x >> 16));
            a2 += w * b2f((ushort)hr[u].y);
            a3 += w * b2f((ushort)(hr[u].y >> 16));
            s += w;
        }
    }
    if (act) {
        float inv = 1.f / fmaxf(s, 1e-9f);
        float4 o;
        o.x = leaky(a0 * inv, oslope);
        o.y = leaky(a1 * inv, oslope);
        o.z = leaky(a2 * inv, oslope);
        o.w = leaky(a3 * inv, oslope);
        *(float4*)(out + (size_t)gw * HD + lane * 4) = o;
    }
}

// final GAT layer: H=2, D=32, HD=64 (bf16 h, load/compute split, U=8)
__global__ __launch_bounds__(256) void aggr_mean_kernel(const ushort* __restrict__ h,
                                                        const float* __restrict__ el,
                                                        const float* __restrict__ er,
                                                        const int* __restrict__ off,
                                                        const int* __restrict__ csr,
                                                        const int* __restrict__ gid,
                                                        float* __restrict__ out_sum,
                                                        float* __restrict__ out_cnt,
                                                        int Nn) {
    int gw = blockIdx.x * 4 + (threadIdx.x >> 6);
    if (gw >= Nn) return;
    int lane = threadIdx.x & 63;
    bool lo32 = lane < 32;
    float erd = lo32 ? er[gw * 2] : er[gw * 2 + 1];
    float acc = 0.f, s = 0.f;
    int e = off[gw], e1 = off[gw + 1];
    for (; e + 8 <= e1; e += 8) {
        int srcs[8];
#pragma unroll
        for (int u = 0; u < 8; u++) srcs[u] = csr[e + u];
        float2 e2[8];
        ushort hu[8];
#pragma unroll
        for (int u = 0; u < 8; u++) {
            e2[u] = *(const float2*)(el + srcs[u] * 2);
            hu[u] = h[(size_t)srcs[u] * 64 + lane];
        }
#pragma unroll
        for (int u = 0; u < 8; u++) {
            float ev = (lo32 ? e2[u].x : e2[u].y) + erd;
            ev = ev >= 0.f ? ev : 0.2f * ev;
            float w = __expf(fminf(ev, 80.f));
            acc += w * b2f(hu[u]);
            s += w;
        }
    }
    if (e < e1) {
        float2 e2[8];
        ushort hu[8];
        bool okk[8];
#pragma unroll
        for (int u = 0; u < 8; u++) {
            int idx = e + u;
            okk[u] = idx < e1;
            int src = csr[okk[u] ? idx : e];
            e2[u] = *(const float2*)(el + src * 2);
            hu[u] = h[(size_t)src * 64 + lane];
        }
#pragma unroll
        for (int u = 0; u < 8; u++) {
            float ev = (lo32 ? e2[u].x : e2[u].y) + erd;
            ev = ev >= 0.f ? ev : 0.2f * ev;
            float w = okk[u] ? __expf(fminf(ev, 80.f)) : 0.f;
            acc += w * b2f(hu[u]);
            s += w;
        }
    }
    float y = acc / fmaxf(s, 1e-9f);
    float part = __shfl_xor(y, 32, 64);
    float hm = 0.5f * (y + part);
    if (lo32) {
        int base = gid ? gid[gw] * 32 : 0;
        atomicAdd(&out_sum[base + lane], hm);
    }
    if (lane == 0 && out_cnt) atomicAdd(&out_cnt[gid[gw]], 1.0f);
}

// ---------------- GraphNorm column stats ----------------
__global__ void colstats_kernel(const float* __restrict__ x,
                                float* __restrict__ sum,
                                float* __restrict__ sumsq, int Nn) {
    int C = blockDim.x, c = threadIdx.x;
    float ls = 0.f, lq = 0.f;
    for (int r = blockIdx.x; r < Nn; r += gridDim.x) {
        float v = x[(size_t)r * C + c];
        ls += v; lq += v * v;
    }
    atomicAdd(&sum[c], ls);
    atomicAdd(&sumsq[c], lq);
}

// GraphNorm apply for readout: writes d_out (per flag) + fp32 mesh input
__global__ void gnorm_apply_ro_kernel(const float* __restrict__ x,
                                      const float* __restrict__ sum,
                                      const float* __restrict__ sumsq,
                                      const float* __restrict__ g,
                                      const float* __restrict__ b,
                                      const float* __restrict__ a,
                                      void* __restrict__ doutv,
                                      const int* __restrict__ flag,
                                      float* __restrict__ rof, int Nn) {
    int c = threadIdx.x;  // C = 32
    float invn = 1.f / (float)Nn;
    float mu = sum[c] * invn, ex2 = sumsq[c] * invn;
    float av = a[c];
    float var = ex2 - 2.f * av * mu * mu + av * av * mu * mu;
    float sc = g[c] * rsqrtf(var + 1e-5f);
    float sh = b[c] - sc * av * mu;
    bool fp32 = (*flag != 0);
    for (int r = blockIdx.x; r < Nn; r += gridDim.x) {
        int i = r * 32 + c;
        float v = x[i] * sc + sh;
        rof[i] = v;
        if (fp32) ((float*)doutv)[15 + i] = v;
        else      ((ushort*)doutv)[15 + i] = f2b(v);
    }
}

// ---------------- readout: segment-mean @ pcls + leaky ----------------
__global__ __launch_bounds__(256) void readout_kernel(const float* __restrict__ ro_sum,
                                                      const float* __restrict__ ro_cnt,
                                                      const float* __restrict__ pcls,
                                                      float* __restrict__ ro_lin, int NGc) {
    int idx = blockIdx.x * blockDim.x + threadIdx.x;
    int g = idx >> 5, c = idx & 31;
    if (g >= NGc) return;
    float inv = 1.f / fmaxf(ro_cnt[g], 1.f);
    float acc = 0.f;
#pragma unroll
    for (int k = 0; k < 32; k++) acc += ro_sum[g * 32 + k] * inv * pcls[k * 32 + c];
    ro_lin[g * 32 + c] = leaky(acc, 0.01f);
}

// ---------------- MFMA GEMM: C(bf16) = gnorm(A) @ B, fused gnfin + elr ----------------
template <int K, int N, int H, int LOGD, bool GN>
__global__ __launch_bounds__(256) void gemm_kernel(const float* __restrict__ A,
                                                   const float* __restrict__ B,
                                                   const float* __restrict__ csum,
                                                   const float* __restrict__ g,
                                                   const float* __restrict__ gb,
                                                   const float* __restrict__ ga,
                                                   const float* __restrict__ al,
                                                   const float* __restrict__ ar,
                                                   ushort* __restrict__ C,
                                                   float* __restrict__ el,
                                                   float* __restrict__ er, int M) {
    constexpr int NT = N / 16;
    constexpr int AROW = 40;
    __shared__ __align__(16) ushort Alds[64 * AROW];
    __shared__ __align__(16) ushort Blds[32 * N];  // swizzled [k/8][n][k%8]
    __shared__ float ScL[256], ShL[256];
    int tid = threadIdx.x;
    int w = tid >> 6, lane = tid & 63, q = lane >> 4, l16 = lane & 15;
    int m0 = blockIdx.x * 64;
    if (GN && tid < K) {
        float invn = 1.f / (float)M;
        float mu = csum[tid] * invn, ex2 = csum[512 + tid] * invn;
        float av = ga[tid];
        float var = ex2 - 2.f * av * mu * mu + av * av * mu * mu;
        float sc = g[tid] * rsqrtf(var + 1e-5f);
        ScL[tid] = sc;
        ShL[tid] = gb[tid] - sc * av * mu;
    }
    float4v acc[NT];
#pragma unroll
    for (int nt = 0; nt < NT; nt++) acc[nt] = (float4v){0.f, 0.f, 0.f, 0.f};

    for (int kc = 0; kc < K; kc += 32) {
        __syncthreads();
        {
#pragma unroll
            for (int it = 0; it < 2; it++) {
                int idx = it * 256 + tid;
                int r = idx >> 3;
                int c4 = (idx & 7) * 4;
                int gr = m0 + r;
                float4 av = {0.f, 0.f, 0.f, 0.f};
                if (gr < M) av = *(const float4*)(A + (size_t)gr * K + kc + c4);
                if (GN) {
                    av.x = av.x * ScL[kc + c4] + ShL[kc + c4];
                    av.y = av.y * ScL[kc + c4 + 1] + ShL[kc + c4 + 1];
                    av.z = av.z * ScL[kc + c4 + 2] + ShL[kc + c4 + 2];
                    av.w = av.w * ScL[kc + c4 + 3] + ShL[kc + c4 + 3];
                }
                uint2 pk;
                pk.x = (uint)f2b(av.x) | ((uint)f2b(av.y) << 16);
                pk.y = (uint)f2b(av.z) | ((uint)f2b(av.w) << 16);
                *(uint2*)(&Alds[r * AROW + c4]) = pk;
            }
        }
        {
            constexpr int PAIRS = 16 * N;
#pragma unroll
            for (int p0 = 0; p0 < PAIRS; p0 += 256) {
                int p = p0 + tid;
                int k_ = p / (N / 2);
                int n0 = (p % (N / 2)) * 2;
                float2 bv = *(const float2*)(B + (size_t)(kc + k_) * N + n0);
                int base = (((k_ >> 3) * N + n0) << 3) + (k_ & 7);
                Blds[base] = f2b(bv.x);
                Blds[base + 8] = f2b(bv.y);
            }
        }
        __syncthreads();
        short8 a = *(const short8*)(&Alds[(w * 16 + l16) * AROW + q * 8]);
#pragma unroll
        for (int nt = 0; nt < NT; nt++) {
            short8 b = *(const short8*)(&Blds[(q * N + nt * 16 + l16) * 8]);
            acc[nt] = __builtin_amdgcn_mfma_f32_16x16x32_bf16(a, b, acc[nt], 0, 0, 0);
        }
    }
    // store C (bf16) + fused el/er (fp32 from acc)
    float pel[4][H], per[4][H];
#pragma unroll
    for (int i = 0; i < 4; i++)
#pragma unroll
        for (int hh = 0; hh < H; hh++) { pel[i][hh] = 0.f; per[i][hh] = 0.f; }
#pragma unroll
    for (int nt = 0; nt < NT; nt++) {
        int col = nt * 16 + l16;
        float alc = al[col], arc = ar[col];
        constexpr int HSH = LOGD - 4;
        int hh = nt >> HSH;
#pragma unroll
        for (int i = 0; i < 4; i++) {
            int row = m0 + w * 16 + q * 4 + i;
            float v = acc[nt][i];
            if (row < M) C[(size_t)row * N + col] = f2b(v);
            pel[i][hh] += v * alc;
            per[i][hh] += v * arc;
        }
    }
#pragma unroll
    for (int i = 0; i < 4; i++) {
#pragma unroll
        for (int hh = 0; hh < H; hh++) {
            float vl = pel[i][hh], vr = per[i][hh];
#pragma unroll
            for (int m = 1; m < 16; m <<= 1) {
                vl += __shfl_xor(vl, m, 64);
                vr += __shfl_xor(vr, m, 64);
            }
            if (l16 == 0) {
                int row = m0 + w * 16 + q * 4 + i;
                if (row < M) { el[row * H + hh] = vl; er[row * H + hh] = vr; }
            }
        }
    }
}

// ---------------- final: node-mean @ mcls ----------------
__global__ __launch_bounds__(64) void final_kernel(const float* __restrict__ msum,
                                                   const float* __restrict__ mcls,
                                                   void* __restrict__ doutv,
                                                   const int* __restrict__ flag, int Nm) {
    int t = threadIdx.x;
    if (t < 15) {
        float inv = 1.f / (float)Nm;
        float acc = 0.f;
#pragma unroll
        for (int c = 0; c < 32; c++) acc += msum[c] * inv * mcls[c * 15 + t];
        if (*flag) ((float*)doutv)[t] = acc;
        else       ((ushort*)doutv)[t] = f2b(acc);
    }
}

extern "C" void kernel_launch(void* const* d_in, const int* in_sizes, int n_in,
                              void* d_out, int out_size, void* d_ws, size_t ws_size,
                              hipStream_t stream) {
    const int NP = 100000, NG = 2000, EP = 800000, NM = 2000, EM = 32000;

    const int* patch_src = (const int*)d_in[1];
    const int* patch_dst = (const int*)d_in[2];
    const int* patch_gid = (const int*)d_in[3];
    const int* mesh_src = (const int*)d_in[4];
    const int* mesh_dst = (const int*)d_in[5];

    char* p = (char*)d_ws;
    auto alloc = [&](size_t bytes) -> char* {
        char* r = p;
        p += (bytes + 255) & ~(size_t)255;
        return r;
    };
    char* zbase = p;
    int* cnt_p = (int*)alloc((size_t)NP * 4);
    int* cursor_p = (int*)alloc((size_t)NP * 4);
    int* cnt_m = (int*)alloc((size_t)NM * 4);
    int* cursor_m = (int*)alloc((size_t)NM * 4);
    float* ro_sum = (float*)alloc((size_t)NG * 32 * 4);
    float* ro_cnt = (float*)alloc((size_t)NG * 4);
    float* msum = (float*)alloc(32 * 4);
    float* colbuf = (float*)alloc(6 * 1024 * 4);
    size_t zbytes = (size_t)(p - zbase);
    int* flag = (int*)alloc(256);
    int* off_p = (int*)alloc((size_t)(NP + 1) * 4);
    int* off_m = (int*)alloc((size_t)(NM + 1) * 4);
    int* bsum_p = (int*)alloc(64 * 4);
    int* bsum_m = (int*)alloc(16 * 4);
    int* csr_p = (int*)alloc((size_t)EP * 4);
    int* csr_m = (int*)alloc((size_t)EM * 4);
    float* el = (float*)alloc((size_t)NP * 4 * 4);
    float* er = (float*)alloc((size_t)NP * 4 * 4);
    ushort* hbuf = (ushort*)alloc((size_t)NP * 256 * 2);   // bf16 gather buffer
    float* gbuf = (float*)alloc((size_t)NP * 256 * 4);
    ushort* hm = (ushort*)alloc((size_t)NM * 256 * 2);     // bf16 gather buffer
    float* gm = (float*)alloc((size_t)NM * 256 * 4);
    float* elm = (float*)alloc((size_t)NM * 4 * 4);
    float* erm = (float*)alloc((size_t)NM * 4 * 4);
    float* ro_lin = (float*)alloc((size_t)NG * 32 * 4);
    float* ro_f = (float*)alloc((size_t)NG * 32 * 4);

    ConvArgs ca;
    float* convp[36];
    int conv_idx[36];
    conv_idx[0] = 0;
    for (int i = 1; i < 36; i++) conv_idx[i] = 5 + i;
    for (int j = 0; j < 36; j++) {
        int ii = conv_idx[j];
        int n = in_sizes[ii];
        float* dd = (float*)alloc((size_t)n * 4);
        ca.s[j] = d_in[ii];
        ca.d[j] = dd;
        ca.n[j] = n;
        convp[j] = dd;
    }
    ca.s[36] = nullptr;
    ca.d[36] = (float*)zbase;
    ca.n[36] = (int)(zbytes / 4);

    const float* xf = convp[0];
    const float *pW1f = convp[1], *pal1f = convp[2], *par1f = convp[3];
    const float *pg1_gf = convp[4], *pg1_bf = convp[5], *pg1_af = convp[6];
    const float *pW2f = convp[7], *pal2f = convp[8], *par2f = convp[9];
    const float *pg2_gf = convp[10], *pg2_bf = convp[11], *pg2_af = convp[12];
    const float *pW3f = convp[13], *pal3f = convp[14], *par3f = convp[15];
    const float* pclsf = convp[16];
    const float *rn_gf = convp[17], *rn_bf2 = convp[18], *rn_af = convp[19];
    const float *mW1f = convp[20], *mal1f = convp[21], *mar1f = convp[22];
    const float *mg1_gf = convp[23], *mg1_bf = convp[24], *mg1_af = convp[25];
    const float *mW2f = convp[26], *mal2f = convp[27], *mar2f = convp[28];
    const float *mg2_gf = convp[29], *mg2_bf = convp[30], *mg2_af = convp[31];
    const float *mW3f = convp[32], *mal3f = convp[33], *mar3f = convp[34];
    const float* mclsf = convp[35];

    convert_kernel<<<dim3(16, 37), 256, 0, stream>>>(ca, (const ushort*)d_in[0], flag);

    const int SBP = (NP + 2047) / 2048, SBM = (NM + 2047) / 2048;
    hist_both<<<512 + 64, 256, 0, stream>>>(patch_dst, cnt_p, EP, mesh_dst, cnt_m, EM, 512);
    scan_both<<<SBP + SBM, 256, 0, stream>>>(cnt_p, off_p, bsum_p, NP, SBP, cnt_m, off_m, bsum_m, NM);
    fixup_both<<<SBP + SBM, 256, 0, stream>>>(bsum_p, off_p, NP, SBP, bsum_m, off_m, NM, SBM);
    scatter_both<<<512 + 64, 256, 0, stream>>>(patch_src, patch_dst, off_p, cursor_p, csr_p, EP,
                                               mesh_src, mesh_dst, off_m, cursor_m, csr_m, EM, 512);

    int gP = (NP + 3) / 4, gM = (NM + 3) / 4;
    int gT = (NP + 63) / 64, gTm = (NM + 63) / 64;
    float* cb0 = colbuf + 0 * 1024;
    float* cb1 = colbuf + 1 * 1024;
    float* cb2 = colbuf + 2 * 1024;
    float* cb3 = colbuf + 3 * 1024;
    float* cb4 = colbuf + 4 * 1024;

    // ---- patch GAT layer 1 ----
    proj1_elr_kernel<<<gP, 256, 0, stream>>>(xf, pW1f, pal1f, par1f, el, er, NP);
    aggr1_fly_kernel<<<gP, 256, 0, stream>>>(xf, pW1f, el, er, off_p, csr_p, gbuf, NP);
    colstats_kernel<<<256, 256, 0, stream>>>(gbuf, cb0, cb0 + 512, NP);

    // ---- patch GAT layer 2 ----
    gemm_kernel<256, 192, 3, 6, true><<<gT, 256, 0, stream>>>(
        gbuf, pW2f, cb0, pg1_gf, pg1_bf, pg1_af, pal2f, par2f, hbuf, el, er, NP);
    aggr4_kernel<3, 6, 192, 4><<<gP, 256, 0, stream>>>(hbuf, el, er, off_p, csr_p, gbuf, NP, 0.01f);
    colstats_kernel<<<256, 192, 0, stream>>>(gbuf, cb1, cb1 + 512, NP);

    // ---- patch GAT layer 3 + readout ----
    gemm_kernel<192, 64, 2, 5, true><<<gT, 256, 0, stream>>>(
        gbuf, pW3f, cb1, pg2_gf, pg2_bf, pg2_af, pal3f, par3f, hbuf, el, er, NP);
    aggr_mean_kernel<<<gP, 256, 0, stream>>>(hbuf, el, er, off_p, csr_p, patch_gid,
                                             ro_sum, ro_cnt, NP);

    readout_kernel<<<(NG * 32 + 255) / 256, 256, 0, stream>>>(ro_sum, ro_cnt, pclsf, ro_lin, NG);
    colstats_kernel<<<64, 32, 0, stream>>>(ro_lin, cb2, cb2 + 512, NG);
    gnorm_apply_ro_kernel<<<64, 32, 0, stream>>>(ro_lin, cb2, cb2 + 512, rn_gf, rn_bf2, rn_af,
                                                 d_out, flag, ro_f, NG);

    // ---- mesh GAT layer 1 ----
    gemm_kernel<32, 256, 4, 6, false><<<gTm, 256, 0, stream>>>(
        ro_f, mW1f, nullptr, nullptr, nullptr, nullptr, mal1f, mar1f, hm, elm, erm, NM);
    aggr4_kernel<4, 6, 256, 4><<<gM, 256, 0, stream>>>(hm, elm, erm, off_m, csr_m, gm, NM, 0.01f);
    colstats_kernel<<<64, 256, 0, stream>>>(gm, cb3, cb3 + 512, NM);

    // ---- mesh GAT layer 2 ----
    gemm_kernel<256, 96, 3, 5, true><<<gTm, 256, 0, stream>>>(
        gm, mW2f, cb3, mg1_gf, mg1_bf, mg1_af, mal2f, mar2f, hm, elm, erm, NM);
    aggr4_kernel<3, 5, 96, 4><<<gM, 256, 0, stream>>>(hm, elm, erm, off_m, csr_m, gm, NM, 0.01f);
    colstats_kernel<<<64, 96, 0, stream>>>(gm, cb4, cb4 + 512, NM);

    // ---- mesh GAT layer 3 ----
    gemm_kernel<96, 64, 2, 5, true><<<gTm, 256, 0, stream>>>(
        gm, mW3f, cb4, mg2_gf, mg2_bf, mg2_af, mal3f, mar3f, hm, elm, erm, NM);
    aggr_mean_kernel<<<gM, 256, 0, stream>>>(hm, elm, erm, off_m, csr_m, nullptr,
                                             msum, nullptr, NM);
    final_kernel<<<1, 64, 0, stream>>>(msum, mclsf, d_out, flag, NM);

    (void)n_in; (void)out_size; (void)ws_size;
}